// Round 15
// baseline (144.123 us; speedup 1.0000x reference)
//
#include <hip/hip_runtime.h>
#include <hip/hip_bf16.h>

// SelfAttention fused pipeline, bf16 MFMA path, K-split flash attention.
// x[4,512,48,48] -> GN(32) -> qkv 1x1 conv -> 8-head attn (N=2304,D=64) -> out proj.
// GN is folded into the QKV GEMM: qkv = (W (.) sc[b]) x + (W sh[b])  (per-channel affine).
//
// ws layout (67.24 MB < 68.16 MB proven safe):
//   xT    [4][2304][512] bf16 @ 0          (raw x cast+transpose; innerT after attn)
//   wq4   [4][1536][512] bf16 @ 9437184    (W_qkv * qs * sc[b], GN+QSCALE folded)
//   po0   [4][2304][512] bf16 @ 15728640   (unnormalized partial O, split 0)
//   po1   [4][2304][512] bf16 @ 25165824   (split 1)
//   vsec  [4][512][2304] bf16 @ 37748736   (d-major, n-PERMUTED per 64-group)
//   qT    [4][8][2304][64] bf16 @ 47185920
//   kT    [4][8][2304][64] bf16 @ 56623104
//   pl    [2][4][8][2304] f32  @ 66060288
//   part  [4][32][36] float2   @ 66650112  (GN partial sums per n-block)
//   biasq [4][1536] f32        @ 66686976  (W * qs * sh[b])
//   wo_bf [512][512] bf16      @ 66711552

typedef unsigned short u16;
typedef unsigned int u32;
typedef __attribute__((ext_vector_type(8))) short bf16x8;
typedef __attribute__((ext_vector_type(4))) float f32x4;
typedef __attribute__((ext_vector_type(8))) unsigned short us8;
typedef __attribute__((ext_vector_type(4))) unsigned short us4;

#define B_ 4
#define C_ 512
#define N_ 2304
#define H_ 8
#define D_ 64
#define G_ 32
#define SPLIT 2
#define NT (N_ / 64 / SPLIT)   // 18 k-tiles per split block

// log2(e)/8: folded into W_q so QK^T lands in exp2 domain.
#define QSCALE 0.1803368801111204f
// No max subtraction: exp2-domain scores |s| <~ 12, exp2(s) <= ~4096 fits f32/bf16;
// softmax is shift-invariant.

__device__ __forceinline__ u16 f2bf(float f) {
  unsigned u = __float_as_uint(f);
  u += 0x7FFFu + ((u >> 16) & 1u);   // RNE
  return (u16)(u >> 16);
}
__device__ __forceinline__ float bf2f(u16 h) {
  return __uint_as_float(((unsigned)h) << 16);
}
__device__ __forceinline__ u32 pack2bf(float lo, float hi) {
  __hip_bfloat162 t = __float22bfloat162_rn(float2{lo, hi});
  u32 r;
  __builtin_memcpy(&r, &t, 4);
  return r;
}

// async global->LDS, 16B per lane. LDS dest = wave-uniform base + lane*16.
__device__ __forceinline__ void gload16(const void* g, void* l) {
  __builtin_amdgcn_global_load_lds(
      reinterpret_cast<const __attribute__((address_space(1))) unsigned int*>(
          reinterpret_cast<unsigned long long>(g)),
      reinterpret_cast<__attribute__((address_space(3))) unsigned int*>(
          static_cast<unsigned int>(reinterpret_cast<unsigned long long>(l))),
      16, 0, 0);
}

// ---------------- x cast + transpose + GN partial sums (single x pass) ----------------
// block = (c-tile 64, n-tile 64, b). Wave w == group quarter (16 channels) -> one
// wave-reduce per group per n-block; partials written deterministically.
__global__ __launch_bounds__(256) void gn_cast_t_stats(
    const float* __restrict__ x, u16* __restrict__ xT, float2* __restrict__ part) {
  __shared__ u16 T[64][72];
  const int c0 = blockIdx.x * 64, n0 = blockIdx.y * 64, b = blockIdx.z;
  const int tid = threadIdx.x;
  const int r = tid >> 2, ch = (tid & 3) * 16;
  const float* src = x + (size_t)(b * C_ + c0 + r) * N_ + n0 + ch;
  float s = 0.f, s2 = 0.f;
  #pragma unroll
  for (int j = 0; j < 16; j += 4) {
    const float4 v = *(const float4*)(src + j);
    s  += v.x + v.y + v.z + v.w;
    s2 += v.x * v.x + v.y * v.y + v.z * v.z + v.w * v.w;
    us4 o; o[0] = f2bf(v.x); o[1] = f2bf(v.y); o[2] = f2bf(v.z); o[3] = f2bf(v.w);
    *(us4*)&T[r][ch + j] = o;
  }
  // wave = rows 16w..16w+15 = one group quarter; reduce across 64 lanes
  #pragma unroll
  for (int off = 32; off; off >>= 1) { s += __shfl_xor(s, off); s2 += __shfl_xor(s2, off); }
  if ((tid & 63) == 0) {
    const int g = (c0 >> 4) + (tid >> 6);
    part[((size_t)(b * G_) + g) * 36 + blockIdx.y] = make_float2(s, s2);
  }
  __syncthreads();
  us8 o1, o2;
  #pragma unroll
  for (int j = 0; j < 8; j++) { o1[j] = T[ch + j][r]; o2[j] = T[ch + 8 + j][r]; }
  u16* dst = xT + (size_t)(b * N_ + n0 + r) * C_ + c0 + ch;
  *(us8*)dst = o1;
  *(us8*)(dst + 8) = o2;
}

// ---------------- weight prep: Ws[b] = W*qs*sc[b] bf16, biasq[b] = W*qs*sh[b] ----------------
// grid (24, 4): 64 o-rows per block, batch bz.
__global__ __launch_bounds__(256) void prep_weights(
    const float* __restrict__ wq, const float* __restrict__ gamma,
    const float* __restrict__ beta, const float2* __restrict__ part,
    u16* __restrict__ wq4, float* __restrict__ biasq) {
  const int bz = blockIdx.y, o0 = blockIdx.x * 64;
  const int tid = threadIdx.x;
  __shared__ float scs[512], shs[512], mrs[64];
  if (tid < 32) {
    const float2* pp = part + (size_t)(bz * G_ + tid) * 36;
    float S = 0.f, S2 = 0.f;
    for (int i = 0; i < 36; i++) { S += pp[i].x; S2 += pp[i].y; }
    const float inv = 1.f / (16.f * N_);
    const float mean = S * inv;
    mrs[tid] = mean;
    mrs[32 + tid] = rsqrtf(S2 * inv - mean * mean + 1e-5f);
  }
  __syncthreads();
  for (int c = tid; c < 512; c += 256) {
    const float sc = mrs[32 + (c >> 4)] * gamma[c];
    scs[c] = sc;
    shs[c] = beta[c] - mrs[c >> 4] * sc;
  }
  __syncthreads();
  const int row = o0 + (tid >> 2);
  const int cq = (tid & 3) * 128;
  const float qs = (row < 512) ? QSCALE : 1.0f;
  const float* wr = wq + (size_t)row * 512;
  u16* wout = wq4 + ((size_t)(bz * 1536) + row) * 512;
  float bsum = 0.f;
  for (int c = cq; c < cq + 128; c += 4) {
    const float4 w = *(const float4*)(wr + c);
    bsum += w.x * shs[c] + w.y * shs[c + 1] + w.z * shs[c + 2] + w.w * shs[c + 3];
    us4 o;
    o[0] = f2bf(w.x * qs * scs[c]);
    o[1] = f2bf(w.y * qs * scs[c + 1]);
    o[2] = f2bf(w.z * qs * scs[c + 2]);
    o[3] = f2bf(w.w * qs * scs[c + 3]);
    *(us4*)&wout[c] = o;
  }
  bsum *= qs;
  bsum += __shfl_xor(bsum, 1);
  bsum += __shfl_xor(bsum, 2);
  if ((tid & 3) == 0) biasq[bz * 1536 + row] = bsum;
}

// ---------------- wo cast ----------------
__global__ __launch_bounds__(256) void cast_wo(const float* __restrict__ wo,
                                               u16* __restrict__ wo_bf) {
  const int i = blockIdx.x * 256 + threadIdx.x;   // 512*512/4 = 65536 us4
  const float4 v = ((const float4*)wo)[i];
  us4 o; o[0] = f2bf(v.x); o[1] = f2bf(v.y); o[2] = f2bf(v.z); o[3] = f2bf(v.w);
  ((us4*)wo_bf)[i] = o;
}

// ---------------- GEMM: C[bz][m][n] = A[m][k] * B[bz][n][k]^T (A,B bf16) ----------------
// m97 structure: linear LDS [128][32], global_load_lds width-16 staging, 2 barriers/k-step.
// MODE 2 (qkv): A batched (wq4 + bz*M*K), bias added; epilogue scatters q->qT, k->kT,
//   v->vsec (d-major, n-PERMUTED per 64-group so attn PV b-frag is one b128).
// MODE 1 (out proj): f32 output + bias.
template <int MODE>
__global__ __launch_bounds__(256) void gemm_bf16(
    const u16* __restrict__ A, const u16* __restrict__ Bb16,
    void* __restrict__ C, const float* __restrict__ bias,
    u16* __restrict__ qT, u16* __restrict__ kT, u16* __restrict__ vout,
    const int M, const int N, const int K) {
  __shared__ u16 As[128][32];
  __shared__ u16 Bs[128][32];
  const int tid = threadIdx.x;
  const int wave = tid >> 6, lane = tid & 63;
  const int l16 = lane & 15, lq = lane >> 4;
  const int m0 = blockIdx.x * 128, n0 = blockIdx.y * 128, bz = blockIdx.z;
  const int wm = (wave >> 1) * 64, wn = (wave & 1) * 64;
  const u16* Ab = A + (MODE == 2 ? (size_t)bz * M * K : 0);
  const u16* Bb = Bb16 + (size_t)bz * N * K;
  const float* bias_b = bias + (MODE == 2 ? bz * M : 0);

  f32x4 acc[4][4];
  #pragma unroll
  for (int mi = 0; mi < 4; mi++)
    #pragma unroll
    for (int ni = 0; ni < 4; ni++) {
      acc[mi][ni][0] = 0.f; acc[mi][ni][1] = 0.f; acc[mi][ni][2] = 0.f; acc[mi][ni][3] = 0.f;
    }

  const int grow = wave * 32 + (lane >> 2);
  const int gcol = (lane & 3) * 8;
  for (int kt = 0; kt < K; kt += 32) {
    __syncthreads();
    gload16(&Ab[(size_t)(m0 + grow) * K + kt + gcol],      &As[wave * 32][0]);
    gload16(&Ab[(size_t)(m0 + grow + 16) * K + kt + gcol], &As[wave * 32 + 16][0]);
    gload16(&Bb[(size_t)(n0 + grow) * K + kt + gcol],      &Bs[wave * 32][0]);
    gload16(&Bb[(size_t)(n0 + grow + 16) * K + kt + gcol], &Bs[wave * 32 + 16][0]);
    __syncthreads();
    bf16x8 af[4], bfr[4];
    #pragma unroll
    for (int mi = 0; mi < 4; mi++) af[mi] = *(const bf16x8*)&As[wm + mi * 16 + l16][lq * 8];
    #pragma unroll
    for (int ni = 0; ni < 4; ni++) bfr[ni] = *(const bf16x8*)&Bs[wn + ni * 16 + l16][lq * 8];
    #pragma unroll
    for (int mi = 0; mi < 4; mi++)
      #pragma unroll
      for (int ni = 0; ni < 4; ni++)
        acc[mi][ni] = __builtin_amdgcn_mfma_f32_16x16x32_bf16(af[mi], bfr[ni], acc[mi][ni], 0, 0, 0);
  }
  #pragma unroll
  for (int mi = 0; mi < 4; mi++) {
    const int row0 = m0 + wm + mi * 16 + lq * 4;
    #pragma unroll
    for (int ni = 0; ni < 4; ni++) {
      const int col = n0 + wn + ni * 16 + l16;
      if (MODE == 1) {
        #pragma unroll
        for (int j = 0; j < 4; j++) {
          const size_t idx = ((size_t)bz * M + row0 + j) * N + col;
          ((float*)C)[idx] = acc[mi][ni][j] + bias_b[row0 + j];
        }
      } else {
        const int which = row0 >> 9;           // 0=q, 1=k, 2=v
        if (which < 2) {
          const int h = (row0 >> 6) & 7, d0 = row0 & 63;
          u16* dst = which ? kT : qT;
          us4 o;
          #pragma unroll
          for (int j = 0; j < 4; j++) o[j] = f2bf(acc[mi][ni][j] + bias_b[row0 + j]);
          *(us4*)&dst[((size_t)((bz * H_ + h) * N_) + col) * D_ + d0] = o;
        } else {
          // n-permute within 64-group: n = g32 + hi*16 + lq2*4 + j -> g32 + lq2*8 + hi*4 + j
          const int cp = (col & ~63) | (col & 32) | (((col >> 2) & 3) << 3) |
                         (((col >> 4) & 1) << 2) | (col & 3);
          #pragma unroll
          for (int j = 0; j < 4; j++)
            vout[((size_t)(bz * 512) + (row0 & 511) + j) * N + cp] =
                f2bf(acc[mi][ni][j] + bias_b[row0 + j]);
        }
      }
    }
  }
}

// ---------------- flash attention: r14 structure (global_load_lds, swizzled source) ----------------
// block = (h, q-tile of 128, b*SPLIT+sp), 8 waves x 16 q-rows, 18 k-tiles.
// LDS [64][64] u16 per matrix; XOR swizzle applied to the GLOBAL source chunk with
// LINEAR LDS dest -> conflict-free staging writes and fragment reads.
// V is n-permuted in GLOBAL (gemm1 epilogue) so PV b-frag is one b128 read.
__global__ __launch_bounds__(512) void attn_kernel15(
    const u16* __restrict__ qT, const u16* __restrict__ kT,
    const u16* __restrict__ vp, u16* __restrict__ po0,
    float* __restrict__ pl) {
  __shared__ u16 Ks[2][64][64];
  __shared__ u16 Vs[2][64][64];

  const int h = blockIdx.x;
  const int b = blockIdx.z >> 1, sp = blockIdx.z & 1;
  const int q0 = blockIdx.y * 128;
  const int tid = threadIdx.x;
  const int wave = tid >> 6, lane = tid & 63;
  const int l16 = lane & 15, lq = lane >> 4;
  const int h3 = l16 & 7;                  // read-side XOR key
  const int kt0 = sp * NT;

  bf16x8 qf[2];
  {
    const u16* qb = qT + ((size_t)((b * H_ + h) * N_ + q0 + wave * 16 + l16)) * D_;
    qf[0] = *(const bf16x8*)(qb + lq * 8);
    qf[1] = *(const bf16x8*)(qb + 32 + lq * 8);
  }

  float l = 0.f;
  f32x4 acc[4];
  #pragma unroll
  for (int di = 0; di < 4; di++) {
    acc[di][0] = 0.f; acc[di][1] = 0.f; acc[di][2] = 0.f; acc[di][3] = 0.f;
  }
  const f32x4 z4 = {0.f, 0.f, 0.f, 0.f};

  const u16* kbase = kT + (size_t)(b * H_ + h) * N_ * D_;
  const u16* vbase = vp + ((size_t)(b * 512) + h * D_) * N_;
  const int srow = wave * 8 + (lane >> 3);
  const int scg  = (((lane & 7) ^ (srow & 7))) * 8;

  gload16(&kbase[(size_t)(kt0 * 64 + srow) * D_ + scg], &Ks[0][wave * 8][0]);
  gload16(&vbase[(size_t)srow * N_ + kt0 * 64 + scg],   &Vs[0][wave * 8][0]);

  int cur = 0;
  for (int t = 0; t < NT; t++) {
    const int kt = kt0 + t;
    __syncthreads();

    if (t + 1 < NT) {
      gload16(&kbase[(size_t)((kt + 1) * 64 + srow) * D_ + scg], &Ks[cur ^ 1][wave * 8][0]);
      gload16(&vbase[(size_t)srow * N_ + (kt + 1) * 64 + scg],   &Vs[cur ^ 1][wave * 8][0]);
    }

    // ---- S^T = K Q^T ----
    f32x4 s[4];
    __builtin_amdgcn_s_setprio(1);
    #pragma unroll
    for (int ni = 0; ni < 4; ni++) {
      const bf16x8 k0 = *(const bf16x8*)&Ks[cur][ni * 16 + l16][(lq ^ h3) * 8];
      const bf16x8 k1 = *(const bf16x8*)&Ks[cur][ni * 16 + l16][((4 | lq) ^ h3) * 8];
      s[ni] = __builtin_amdgcn_mfma_f32_16x16x32_bf16(k0, qf[0], z4, 0, 0, 0);
      s[ni] = __builtin_amdgcn_mfma_f32_16x16x32_bf16(k1, qf[1], s[ni], 0, 0, 0);
    }
    __builtin_amdgcn_s_setprio(0);

    // ---- p = exp2(s); l in-lane; pack directly into PV a-frag words ----
    union { u32 w[4]; bf16x8 v; } af[2];
    float rs = 0.f;
    #pragma unroll
    for (int ni = 0; ni < 4; ni++) {
      const float p0 = __builtin_amdgcn_exp2f(s[ni][0]);
      const float p1 = __builtin_amdgcn_exp2f(s[ni][1]);
      const float p2 = __builtin_amdgcn_exp2f(s[ni][2]);
      const float p3 = __builtin_amdgcn_exp2f(s[ni][3]);
      rs += (p0 + p1) + (p2 + p3);
      af[ni >> 1].w[(ni & 1) * 2]     = pack2bf(p0, p1);
      af[ni >> 1].w[(ni & 1) * 2 + 1] = pack2bf(p2, p3);
    }
    l += rs;

    // ---- PV ----
    __builtin_amdgcn_s_setprio(1);
    #pragma unroll
    for (int kh = 0; kh < 2; kh++)
      #pragma unroll
      for (int di = 0; di < 4; di++) {
        const bf16x8 vf = *(const bf16x8*)&Vs[cur][di * 16 + l16][(((kh << 2) | lq) ^ h3) * 8];
        acc[di] = __builtin_amdgcn_mfma_f32_16x16x32_bf16(af[kh].v, vf, acc[di], 0, 0, 0);
      }
    __builtin_amdgcn_s_setprio(0);

    cur ^= 1;
  }

  // ---- epilogue: write unnormalized partial O (bf16) + partial l ----
  u16* po = po0 + (size_t)sp * ((size_t)B_ * N_ * 512);
  l += __shfl_xor(l, 16);
  l += __shfl_xor(l, 32);
  if (lq == 0) {
    const int n = q0 + wave * 16 + l16;
    pl[((size_t)((sp * B_ + b) * H_) + h) * N_ + n] = l;
  }
  #pragma unroll
  for (int di = 0; di < 4; di++)
    #pragma unroll
    for (int j = 0; j < 4; j++) {
      const int n = q0 + wave * 16 + lq * 4 + j;
      po[((size_t)(b * N_) + n) * 512 + h * D_ + di * 16 + l16] = f2bf(acc[di][j]);
    }
}

// ---------------- combine: innerT = (po0+po1) * 1/(pl0+pl1), bf16 ----------------
__global__ __launch_bounds__(256) void combine_norm(
    const u16* __restrict__ po0, const u16* __restrict__ po1,
    const float* __restrict__ pl, u16* __restrict__ innerT) {
  const int bn = blockIdx.x * 4 + (threadIdx.x >> 6);   // b*N + n
  const int b = bn / N_, n = bn - b * N_;
  const int c0 = (threadIdx.x & 63) * 8;
  const int h = c0 >> 6;
  const size_t lidx = ((size_t)(b * H_) + h) * N_ + n;
  const float rl = 1.0f / (pl[lidx] + pl[lidx + (size_t)B_ * H_ * N_]);
  const size_t base = (size_t)bn * 512 + c0;
  const us8 a = *(const us8*)&po0[base];
  const us8 c = *(const us8*)&po1[base];
  us8 o;
  #pragma unroll
  for (int j = 0; j < 8; j++) o[j] = f2bf((bf2f(a[j]) + bf2f(c[j])) * rl);
  *(us8*)&innerT[base] = o;
}

extern "C" void kernel_launch(void* const* d_in, const int* in_sizes, int n_in,
                              void* d_out, int out_size, void* d_ws, size_t ws_size,
                              hipStream_t stream) {
  const float* x     = (const float*)d_in[0];
  const float* gamma = (const float*)d_in[1];
  const float* beta  = (const float*)d_in[2];
  const float* w_qkv = (const float*)d_in[3];
  const float* w_out = (const float*)d_in[4];
  const float* b_out = (const float*)d_in[5];
  float* out = (float*)d_out;

  char* ws = (char*)d_ws;
  u16*    xT     = (u16*)(ws + 0);          // innerT after attn
  u16*    wq4    = (u16*)(ws + 9437184);
  u16*    po0    = (u16*)(ws + 15728640);
  u16*    po1    = (u16*)(ws + 25165824);
  u16*    vsec   = (u16*)(ws + 37748736);
  u16*    qT     = (u16*)(ws + 47185920);
  u16*    kT     = (u16*)(ws + 56623104);
  float*  pl     = (float*)(ws + 66060288);
  float2* part   = (float2*)(ws + 66650112);
  float*  biasq  = (float*)(ws + 66686976);
  u16*    wo_bf  = (u16*)(ws + 66711552);
  u16*    innerT = xT;                      // alias; xT dead after gemm1

  gn_cast_t_stats<<<dim3(C_ / 64, N_ / 64, B_), dim3(256), 0, stream>>>(x, xT, part);
  prep_weights<<<dim3(24, B_), dim3(256), 0, stream>>>(w_qkv, gamma, beta, part, wq4, biasq);
  cast_wo<<<dim3(256), dim3(256), 0, stream>>>(w_out, wo_bf);
  gemm_bf16<2><<<dim3(12, 18, B_), dim3(256), 0, stream>>>(
      wq4, xT, nullptr, biasq, qT, kT, vsec, 1536, N_, C_);
  attn_kernel15<<<dim3(H_, N_ / 128, B_ * SPLIT), dim3(512), 0, stream>>>(qT, kT, vsec, po0, pl);
  combine_norm<<<dim3(B_ * N_ / 4), dim3(256), 0, stream>>>(po0, po1, pl, innerT);
  gemm_bf16<1><<<dim3(4, 18, B_), dim3(256), 0, stream>>>(
      wo_bf, innerT, (void*)out, b_out, nullptr, nullptr, nullptr, C_, N_, C_);
}

// Round 16
// 139.125 us; speedup vs baseline: 1.0359x; 1.0359x over previous
//
#include <hip/hip_runtime.h>
#include <hip/hip_bf16.h>

// SelfAttention fused pipeline, bf16 MFMA path, K-split flash attention.
// x[4,512,48,48] -> GN(32) -> qkv 1x1 conv -> 8-head attn (N=2304,D=64) -> out proj.
//
// ws layout (67.18 MB < 68.16 MB proven safe):
//   innerT[4][2304][512] bf16 @ 0          (aliases xnT; xnT dead after gemm1)
//   wq_bf [1536][512] bf16    @ 9437184
//   po0   [4][2304][512] bf16 @ 11010048   (unnormalized partial O, split 0)
//   po1   [4][2304][512] bf16 @ 20447232   (split 1)
//   vsec  [4][512][2304] bf16 @ 37748736   (d-major, n-PERMUTED per 64-group)
//   qT    [4][8][2304][64] bf16 @ 47185920 (QSCALE folded at cast)
//   kT    [4][8][2304][64] bf16 @ 56623104
//   pl    [2][4][8][2304] f32  @ 66060288
//   part  [128][4] float2      @ 66650112  (GN partial sums)
//   wo_bf [512][512] bf16      @ 66655232

typedef unsigned short u16;
typedef unsigned int u32;
typedef __attribute__((ext_vector_type(8))) short bf16x8;
typedef __attribute__((ext_vector_type(4))) float f32x4;
typedef __attribute__((ext_vector_type(8))) unsigned short us8;
typedef __attribute__((ext_vector_type(4))) unsigned short us4;

#define B_ 4
#define C_ 512
#define N_ 2304
#define H_ 8
#define D_ 64
#define G_ 32
#define SPLIT 2
#define NT (N_ / 64 / SPLIT)   // 18 k-tiles per split block

// log2(e)/8: folded into W_q at cast so QK^T lands in exp2 domain.
#define QSCALE 0.1803368801111204f
// No max subtraction: exp2-domain scores |s| <~ 12, exp2(s) <= ~4096 fits f32/bf16;
// softmax is shift-invariant.

__device__ __forceinline__ u16 f2bf(float f) {
  unsigned u = __float_as_uint(f);
  u += 0x7FFFu + ((u >> 16) & 1u);   // RNE
  return (u16)(u >> 16);
}
__device__ __forceinline__ float bf2f(u16 h) {
  return __uint_as_float(((unsigned)h) << 16);
}
__device__ __forceinline__ u32 pack2bf(float lo, float hi) {
  __hip_bfloat162 t = __float22bfloat162_rn(float2{lo, hi});
  u32 r;
  __builtin_memcpy(&r, &t, 4);
  return r;
}

// async global->LDS, 16B per lane. LDS dest = wave-uniform base + lane*16.
__device__ __forceinline__ void gload16(const void* g, void* l) {
  __builtin_amdgcn_global_load_lds(
      reinterpret_cast<const __attribute__((address_space(1))) unsigned int*>(
          reinterpret_cast<unsigned long long>(g)),
      reinterpret_cast<__attribute__((address_space(3))) unsigned int*>(
          static_cast<unsigned int>(reinterpret_cast<unsigned long long>(l))),
      16, 0, 0);
}

// ---------------- weight cast (q rows pre-scaled by QSCALE) ----------------
__global__ __launch_bounds__(256) void cast_weights(
    const float* __restrict__ wq, const float* __restrict__ wo,
    u16* __restrict__ wq_bf, u16* __restrict__ wo_bf) {
  const int n1 = 1536 * 512 / 4, n2 = 512 * 512 / 4;
  const int nq = 512 * 512 / 4;   // q section in float4 units
  for (int i = blockIdx.x * 256 + threadIdx.x; i < n1 + n2; i += gridDim.x * 256) {
    const float4 v = (i < n1) ? ((const float4*)wq)[i] : ((const float4*)wo)[i - n1];
    const float sc = (i < nq) ? QSCALE : 1.0f;
    us4 o; o[0] = f2bf(v.x * sc); o[1] = f2bf(v.y * sc); o[2] = f2bf(v.z * sc); o[3] = f2bf(v.w * sc);
    if (i < n1) ((us4*)wq_bf)[i] = o; else ((us4*)wo_bf)[i - n1] = o;
  }
}

// ---------------- GN partial sums: 4 blocks per (b,g), deterministic ----------------
__global__ __launch_bounds__(256) void gn_stats_part(const float* __restrict__ x,
                                                     float2* __restrict__ part) {
  const int bg = blockIdx.x >> 2, q = blockIdx.x & 3;
  const float* p = x + (size_t)bg * 16 * N_ + (size_t)q * (16 * N_ / 4);
  float s = 0.f, s2 = 0.f;
  for (int i = threadIdx.x; i < 16 * N_ / 16; i += 256) {   // 2304 float4 per quarter
    const float4 v = ((const float4*)p)[i];
    s  += v.x + v.y + v.z + v.w;
    s2 += v.x * v.x + v.y * v.y + v.z * v.z + v.w * v.w;
  }
  #pragma unroll
  for (int off = 32; off; off >>= 1) { s += __shfl_down(s, off); s2 += __shfl_down(s2, off); }
  __shared__ float red[8];
  if ((threadIdx.x & 63) == 0) { red[(threadIdx.x >> 6) * 2] = s; red[(threadIdx.x >> 6) * 2 + 1] = s2; }
  __syncthreads();
  if (threadIdx.x == 0) {
    float S = 0.f, S2 = 0.f;
    for (int w = 0; w < 4; w++) { S += red[w * 2]; S2 += red[w * 2 + 1]; }
    part[blockIdx.x] = make_float2(S, S2);
  }
}

// ---------------- GN apply + transpose -> xnT[b][n][c] bf16 ----------------
__global__ __launch_bounds__(256) void gn_apply_t(
    const float* __restrict__ x, const float2* __restrict__ part,
    const float* __restrict__ gamma, const float* __restrict__ beta,
    u16* __restrict__ xnT) {
  __shared__ u16 T[64][72];
  const int c0 = blockIdx.x * 64, n0 = blockIdx.y * 64, b = blockIdx.z;
  const int r = threadIdx.x >> 2, ch = (threadIdx.x & 3) * 16;
  const int cc = c0 + r;
  const float2* pp = part + (size_t)(b * G_ + (cc >> 4)) * 4;
  const float S  = pp[0].x + pp[1].x + pp[2].x + pp[3].x;
  const float S2 = pp[0].y + pp[1].y + pp[2].y + pp[3].y;
  const float inv = 1.f / (16.f * N_);
  const float mean = S * inv;
  const float rstd = rsqrtf(S2 * inv - mean * mean + 1e-5f);
  const float sc = rstd * gamma[cc];
  const float sh = beta[cc] - mean * sc;
  const float* src = x + (size_t)(b * C_ + cc) * N_ + n0 + ch;
  #pragma unroll
  for (int j = 0; j < 16; j += 4) {
    const float4 v = *(const float4*)(src + j);
    us4 o; o[0] = f2bf(v.x * sc + sh); o[1] = f2bf(v.y * sc + sh);
    o[2] = f2bf(v.z * sc + sh); o[3] = f2bf(v.w * sc + sh);
    *(us4*)&T[r][ch + j] = o;
  }
  __syncthreads();
  us8 o1, o2;
  #pragma unroll
  for (int j = 0; j < 8; j++) { o1[j] = T[ch + j][r]; o2[j] = T[ch + 8 + j][r]; }
  u16* dst = xnT + (size_t)(b * N_ + n0 + r) * C_ + c0 + ch;
  *(us8*)dst = o1;
  *(us8*)(dst + 8) = o2;
}

// ---------------- GEMM: C[bz][m][n] = A[m][k] * B[bz][n][k]^T (A,B bf16) ----------------
// m97 structure: linear LDS [128][32], global_load_lds width-16 staging, 2 barriers/k-step.
// MODE 2 (qkv): epilogue scatters q->qT, k->kT ([b][h][n][d]), v->vsec
//   (d-major, n-PERMUTED within each 64-col group so attn PV b-frag is one b128).
// MODE 1 (out proj): f32 output + bias.
template <int MODE>
__global__ __launch_bounds__(256) void gemm_bf16(
    const u16* __restrict__ A, const u16* __restrict__ Bb16,
    void* __restrict__ C, const float* __restrict__ bias,
    u16* __restrict__ qT, u16* __restrict__ kT, u16* __restrict__ vout,
    const int M, const int N, const int K) {
  __shared__ u16 As[128][32];
  __shared__ u16 Bs[128][32];
  const int tid = threadIdx.x;
  const int wave = tid >> 6, lane = tid & 63;
  const int l16 = lane & 15, lq = lane >> 4;
  const int m0 = blockIdx.x * 128, n0 = blockIdx.y * 128, bz = blockIdx.z;
  const int wm = (wave >> 1) * 64, wn = (wave & 1) * 64;
  const u16* Bb = Bb16 + (size_t)bz * N * K;

  f32x4 acc[4][4];
  #pragma unroll
  for (int mi = 0; mi < 4; mi++)
    #pragma unroll
    for (int ni = 0; ni < 4; ni++) {
      acc[mi][ni][0] = 0.f; acc[mi][ni][1] = 0.f; acc[mi][ni][2] = 0.f; acc[mi][ni][3] = 0.f;
    }

  const int grow = wave * 32 + (lane >> 2);   // global row this lane fetches (first shot)
  const int gcol = (lane & 3) * 8;            // u16 col offset
  for (int kt = 0; kt < K; kt += 32) {
    __syncthreads();
    gload16(&A[(size_t)(m0 + grow) * K + kt + gcol],      &As[wave * 32][0]);
    gload16(&A[(size_t)(m0 + grow + 16) * K + kt + gcol], &As[wave * 32 + 16][0]);
    gload16(&Bb[(size_t)(n0 + grow) * K + kt + gcol],      &Bs[wave * 32][0]);
    gload16(&Bb[(size_t)(n0 + grow + 16) * K + kt + gcol], &Bs[wave * 32 + 16][0]);
    __syncthreads();
    bf16x8 af[4], bfr[4];
    #pragma unroll
    for (int mi = 0; mi < 4; mi++) af[mi] = *(const bf16x8*)&As[wm + mi * 16 + l16][lq * 8];
    #pragma unroll
    for (int ni = 0; ni < 4; ni++) bfr[ni] = *(const bf16x8*)&Bs[wn + ni * 16 + l16][lq * 8];
    #pragma unroll
    for (int mi = 0; mi < 4; mi++)
      #pragma unroll
      for (int ni = 0; ni < 4; ni++)
        acc[mi][ni] = __builtin_amdgcn_mfma_f32_16x16x32_bf16(af[mi], bfr[ni], acc[mi][ni], 0, 0, 0);
  }
  #pragma unroll
  for (int mi = 0; mi < 4; mi++) {
    const int row0 = m0 + wm + mi * 16 + lq * 4;
    #pragma unroll
    for (int ni = 0; ni < 4; ni++) {
      const int col = n0 + wn + ni * 16 + l16;
      if (MODE == 1) {
        #pragma unroll
        for (int j = 0; j < 4; j++) {
          const size_t idx = ((size_t)bz * M + row0 + j) * N + col;
          ((float*)C)[idx] = acc[mi][ni][j] + bias[row0 + j];
        }
      } else {
        const int which = row0 >> 9;           // 0=q, 1=k, 2=v
        if (which < 2) {
          const int h = (row0 >> 6) & 7, d0 = row0 & 63;
          u16* dst = which ? kT : qT;
          us4 o;
          #pragma unroll
          for (int j = 0; j < 4; j++) o[j] = f2bf(acc[mi][ni][j]);
          *(us4*)&dst[((size_t)((bz * H_ + h) * N_) + col) * D_ + d0] = o;
        } else {
          // n-permute within 64-group: n = g32 + hi*16 + lq2*4 + j -> g32 + lq2*8 + hi*4 + j
          const int cp = (col & ~63) | (col & 32) | (((col >> 2) & 3) << 3) |
                         (((col >> 4) & 1) << 2) | (col & 3);
          #pragma unroll
          for (int j = 0; j < 4; j++)
            vout[((size_t)(bz * 512) + (row0 & 511) + j) * N + cp] = f2bf(acc[mi][ni][j]);
        }
      }
    }
  }
}

// ---------------- flash attention v16: counted-vmcnt 3-buffer ring (T4) ----------------
// block = (h, q-tile of 128, b*SPLIT+sp), 8 waves x 16 q-rows, 18 k-tiles.
// Per tile each wave issues 2 global_load_lds (K,V) into a 3-deep LDS ring,
// prefetch distance 2. Raw s_barrier + inline s_waitcnt vmcnt(2) in-loop (never 0):
// tile t's loads are guaranteed landed while t+1/t+2 stay in flight across the
// barrier. vmcnt(0) only at the last tile. Prefetch issued AFTER the barrier so
// the target buffer (used by tile t-1) is no longer being read by any wave.
// XOR swizzle on the GLOBAL source chunk, linear LDS dest (r13/r14 layout);
// V n-permuted in global (gemm1 epilogue) so PV b-frag is one b128 read.
__global__ __launch_bounds__(512) void attn_kernel16(
    const u16* __restrict__ qT, const u16* __restrict__ kT,
    const u16* __restrict__ vp, u16* __restrict__ po0,
    float* __restrict__ pl) {
  __shared__ u16 Ks[3][64][64];
  __shared__ u16 Vs[3][64][64];

  const int h = blockIdx.x;
  const int b = blockIdx.z >> 1, sp = blockIdx.z & 1;
  const int q0 = blockIdx.y * 128;
  const int tid = threadIdx.x;
  const int wave = tid >> 6, lane = tid & 63;
  const int l16 = lane & 15, lq = lane >> 4;
  const int h3 = l16 & 7;                  // read-side XOR key
  const int kt0 = sp * NT;

  // Q fragments (B-operand: lane row = q_local = l16), 16 rows per wave
  bf16x8 qf[2];
  {
    const u16* qb = qT + ((size_t)((b * H_ + h) * N_ + q0 + wave * 16 + l16)) * D_;
    qf[0] = *(const bf16x8*)(qb + lq * 8);
    qf[1] = *(const bf16x8*)(qb + 32 + lq * 8);
  }

  float l = 0.f;
  f32x4 acc[4];
  #pragma unroll
  for (int di = 0; di < 4; di++) {
    acc[di][0] = 0.f; acc[di][1] = 0.f; acc[di][2] = 0.f; acc[di][3] = 0.f;
  }
  const f32x4 z4 = {0.f, 0.f, 0.f, 0.f};

  const u16* kbase = kT + (size_t)(b * H_ + h) * N_ * D_;
  const u16* vbase = vp + ((size_t)(b * 512) + h * D_) * N_;
  // staging: wave w covers rows w*8..w*8+7 of the 64x64 tile (1KB per issue).
  const int srow = wave * 8 + (lane >> 3);
  const int scg  = (((lane & 7) ^ (srow & 7))) * 8;   // pre-swizzled global chunk

  // prologue: stage tiles kt0 -> buf0, kt0+1 -> buf1
  gload16(&kbase[(size_t)(kt0 * 64 + srow) * D_ + scg], &Ks[0][wave * 8][0]);
  gload16(&vbase[(size_t)srow * N_ + kt0 * 64 + scg],   &Vs[0][wave * 8][0]);
  gload16(&kbase[(size_t)((kt0 + 1) * 64 + srow) * D_ + scg], &Ks[1][wave * 8][0]);
  gload16(&vbase[(size_t)srow * N_ + (kt0 + 1) * 64 + scg],   &Vs[1][wave * 8][0]);

  int cur = 0;
  for (int t = 0; t < NT; t++) {
    // counted wait: tile t's 2 loads done; t+1 (and t+2 once issued) stay in flight.
    if (t == NT - 1) asm volatile("s_waitcnt vmcnt(0)" ::: "memory");
    else             asm volatile("s_waitcnt vmcnt(2)" ::: "memory");
    __builtin_amdgcn_s_barrier();
    __builtin_amdgcn_sched_barrier(0);

    if (t + 2 < NT) {
      const int kt2 = kt0 + t + 2;
      const int bw = (cur >= 1) ? cur - 1 : 2;   // (cur+2)%3
      gload16(&kbase[(size_t)(kt2 * 64 + srow) * D_ + scg], &Ks[bw][wave * 8][0]);
      gload16(&vbase[(size_t)srow * N_ + kt2 * 64 + scg],   &Vs[bw][wave * 8][0]);
    }

    // ---- S^T = K Q^T ----
    f32x4 s[4];
    __builtin_amdgcn_s_setprio(1);
    #pragma unroll
    for (int ni = 0; ni < 4; ni++) {
      const bf16x8 k0 = *(const bf16x8*)&Ks[cur][ni * 16 + l16][(lq ^ h3) * 8];
      const bf16x8 k1 = *(const bf16x8*)&Ks[cur][ni * 16 + l16][((4 | lq) ^ h3) * 8];
      s[ni] = __builtin_amdgcn_mfma_f32_16x16x32_bf16(k0, qf[0], z4, 0, 0, 0);
      s[ni] = __builtin_amdgcn_mfma_f32_16x16x32_bf16(k1, qf[1], s[ni], 0, 0, 0);
    }
    __builtin_amdgcn_s_setprio(0);

    // ---- p = exp2(s); l in-lane; pack directly into PV a-frag words ----
    union { u32 w[4]; bf16x8 v; } af[2];   // [kh]
    float rs = 0.f;
    #pragma unroll
    for (int ni = 0; ni < 4; ni++) {
      const float p0 = __builtin_amdgcn_exp2f(s[ni][0]);
      const float p1 = __builtin_amdgcn_exp2f(s[ni][1]);
      const float p2 = __builtin_amdgcn_exp2f(s[ni][2]);
      const float p3 = __builtin_amdgcn_exp2f(s[ni][3]);
      rs += (p0 + p1) + (p2 + p3);
      af[ni >> 1].w[(ni & 1) * 2]     = pack2bf(p0, p1);
      af[ni >> 1].w[(ni & 1) * 2 + 1] = pack2bf(p2, p3);
    }
    l += rs;

    // ---- PV: V b-frags one b128 each ----
    __builtin_amdgcn_s_setprio(1);
    #pragma unroll
    for (int kh = 0; kh < 2; kh++)
      #pragma unroll
      for (int di = 0; di < 4; di++) {
        const bf16x8 vf = *(const bf16x8*)&Vs[cur][di * 16 + l16][(((kh << 2) | lq) ^ h3) * 8];
        acc[di] = __builtin_amdgcn_mfma_f32_16x16x32_bf16(af[kh].v, vf, acc[di], 0, 0, 0);
      }
    __builtin_amdgcn_s_setprio(0);

    cur = (cur == 2) ? 0 : cur + 1;
  }

  // ---- epilogue: write unnormalized partial O (bf16) + partial l ----
  u16* po = po0 + (size_t)sp * ((size_t)B_ * N_ * 512);
  l += __shfl_xor(l, 16);
  l += __shfl_xor(l, 32);
  if (lq == 0) {
    const int n = q0 + wave * 16 + l16;
    pl[((size_t)((sp * B_ + b) * H_) + h) * N_ + n] = l;
  }
  #pragma unroll
  for (int di = 0; di < 4; di++)
    #pragma unroll
    for (int j = 0; j < 4; j++) {
      const int n = q0 + wave * 16 + lq * 4 + j;
      po[((size_t)(b * N_) + n) * 512 + h * D_ + di * 16 + l16] = f2bf(acc[di][j]);
    }
}

// ---------------- combine: innerT = (po0+po1) * 1/(pl0+pl1), bf16 ----------------
__global__ __launch_bounds__(256) void combine_norm(
    const u16* __restrict__ po0, const u16* __restrict__ po1,
    const float* __restrict__ pl, u16* __restrict__ innerT) {
  const int bn = blockIdx.x * 4 + (threadIdx.x >> 6);   // b*N + n
  const int b = bn / N_, n = bn - b * N_;
  const int c0 = (threadIdx.x & 63) * 8;
  const int h = c0 >> 6;
  const size_t lidx = ((size_t)(b * H_) + h) * N_ + n;
  const float rl = 1.0f / (pl[lidx] + pl[lidx + (size_t)B_ * H_ * N_]);
  const size_t base = (size_t)bn * 512 + c0;
  const us8 a = *(const us8*)&po0[base];
  const us8 c = *(const us8*)&po1[base];
  us8 o;
  #pragma unroll
  for (int j = 0; j < 8; j++) o[j] = f2bf((bf2f(a[j]) + bf2f(c[j])) * rl);
  *(us8*)&innerT[base] = o;
}

extern "C" void kernel_launch(void* const* d_in, const int* in_sizes, int n_in,
                              void* d_out, int out_size, void* d_ws, size_t ws_size,
                              hipStream_t stream) {
  const float* x     = (const float*)d_in[0];
  const float* gamma = (const float*)d_in[1];
  const float* beta  = (const float*)d_in[2];
  const float* w_qkv = (const float*)d_in[3];
  const float* w_out = (const float*)d_in[4];
  const float* b_out = (const float*)d_in[5];
  float* out = (float*)d_out;

  char* ws = (char*)d_ws;
  u16*    innerT = (u16*)(ws + 0);          // also xnT before attn
  u16*    wq_bf  = (u16*)(ws + 9437184);
  u16*    po0    = (u16*)(ws + 11010048);
  u16*    po1    = (u16*)(ws + 20447232);
  u16*    vsec   = (u16*)(ws + 37748736);
  u16*    qT     = (u16*)(ws + 47185920);
  u16*    kT     = (u16*)(ws + 56623104);
  float*  pl     = (float*)(ws + 66060288);
  float2* part   = (float2*)(ws + 66650112);
  u16*    wo_bf  = (u16*)(ws + 66655232);
  u16*    xnT    = innerT;                  // alias; xnT dead after gemm1

  cast_weights<<<dim3(256), dim3(256), 0, stream>>>(w_qkv, w_out, wq_bf, wo_bf);
  gn_stats_part<<<dim3(B_ * G_ * 4), dim3(256), 0, stream>>>(x, part);
  gn_apply_t<<<dim3(C_ / 64, N_ / 64, B_), dim3(256), 0, stream>>>(x, part, gamma, beta, xnT);
  gemm_bf16<2><<<dim3(12, 18, B_), dim3(256), 0, stream>>>(
      wq_bf, xnT, nullptr, nullptr, qT, kT, vsec, 1536, N_, C_);
  attn_kernel16<<<dim3(H_, N_ / 128, B_ * SPLIT), dim3(512), 0, stream>>>(qT, kT, vsec, po0, pl);
  combine_norm<<<dim3(B_ * N_ / 4), dim3(256), 0, stream>>>(po0, po1, pl, innerT);
  gemm_bf16<1><<<dim3(4, 18, B_), dim3(256), 0, stream>>>(
      wo_bf, innerT, (void*)out, b_out, nullptr, nullptr, nullptr, C_, N_, C_);
}

// Round 17
// 138.475 us; speedup vs baseline: 1.0408x; 1.0047x over previous
//
#include <hip/hip_runtime.h>
#include <hip/hip_bf16.h>

// SelfAttention fused pipeline, bf16 MFMA path, K-split flash attention.
// x[4,512,48,48] -> GN(32) -> qkv 1x1 conv -> 8-head attn (N=2304,D=64) -> out proj.
//
// ws layout (67.77 MB < 68.16 MB proven safe):
//   xnT   [4][2304][512] bf16 @ 0          (gemm1 B input; po0 aliases it during attn)
//   wq_bf [1536][512] bf16    @ 9437184    (dead after gemm1; po1 region)
//   po0..po3 [4][2304][512] bf16 @ 0, 9437184, 18874368, 28311552  (during/after attn)
//   vsec  [4][512][2304] bf16 @ 37748736   (d-major, n-PERMUTED per 64-group)
//   qT    [4][8][2304][64] bf16 @ 47185920 (QSCALE folded at cast; innerT after attn)
//   kT    [4][8][2304][64] bf16 @ 56623104
//   pl    [4][4][8][2304] f32  @ 66060288
//   part  [128][4] float2      @ 67239936  (GN partial sums)
//   wo_bf [512][512] bf16      @ 67244032

typedef unsigned short u16;
typedef unsigned int u32;
typedef __attribute__((ext_vector_type(8))) short bf16x8;
typedef __attribute__((ext_vector_type(4))) float f32x4;
typedef __attribute__((ext_vector_type(8))) unsigned short us8;
typedef __attribute__((ext_vector_type(4))) unsigned short us4;

#define B_ 4
#define C_ 512
#define N_ 2304
#define H_ 8
#define D_ 64
#define G_ 32
#define SPLIT 4
#define NT (N_ / 64 / SPLIT)   // 9 k-tiles per split block

// log2(e)/8: folded into W_q at cast so QK^T lands in exp2 domain.
#define QSCALE 0.1803368801111204f
// No max subtraction: exp2-domain scores |s| <~ 12, exp2(s) <= ~4096 fits f32/bf16;
// softmax is shift-invariant.

__device__ __forceinline__ u16 f2bf(float f) {
  unsigned u = __float_as_uint(f);
  u += 0x7FFFu + ((u >> 16) & 1u);   // RNE
  return (u16)(u >> 16);
}
__device__ __forceinline__ float bf2f(u16 h) {
  return __uint_as_float(((unsigned)h) << 16);
}
__device__ __forceinline__ u32 pack2bf(float lo, float hi) {
  __hip_bfloat162 t = __float22bfloat162_rn(float2{lo, hi});
  u32 r;
  __builtin_memcpy(&r, &t, 4);
  return r;
}

// async global->LDS, 16B per lane. LDS dest = wave-uniform base + lane*16.
__device__ __forceinline__ void gload16(const void* g, void* l) {
  __builtin_amdgcn_global_load_lds(
      reinterpret_cast<const __attribute__((address_space(1))) unsigned int*>(
          reinterpret_cast<unsigned long long>(g)),
      reinterpret_cast<__attribute__((address_space(3))) unsigned int*>(
          static_cast<unsigned int>(reinterpret_cast<unsigned long long>(l))),
      16, 0, 0);
}

// ---------------- weight cast (q rows pre-scaled by QSCALE) ----------------
__global__ __launch_bounds__(256) void cast_weights(
    const float* __restrict__ wq, const float* __restrict__ wo,
    u16* __restrict__ wq_bf, u16* __restrict__ wo_bf) {
  const int n1 = 1536 * 512 / 4, n2 = 512 * 512 / 4;
  const int nq = 512 * 512 / 4;   // q section in float4 units
  for (int i = blockIdx.x * 256 + threadIdx.x; i < n1 + n2; i += gridDim.x * 256) {
    const float4 v = (i < n1) ? ((const float4*)wq)[i] : ((const float4*)wo)[i - n1];
    const float sc = (i < nq) ? QSCALE : 1.0f;
    us4 o; o[0] = f2bf(v.x * sc); o[1] = f2bf(v.y * sc); o[2] = f2bf(v.z * sc); o[3] = f2bf(v.w * sc);
    if (i < n1) ((us4*)wq_bf)[i] = o; else ((us4*)wo_bf)[i - n1] = o;
  }
}

// ---------------- GN partial sums: 4 blocks per (b,g), deterministic ----------------
__global__ __launch_bounds__(256) void gn_stats_part(const float* __restrict__ x,
                                                     float2* __restrict__ part) {
  const int bg = blockIdx.x >> 2, q = blockIdx.x & 3;
  const float* p = x + (size_t)bg * 16 * N_ + (size_t)q * (16 * N_ / 4);
  float s = 0.f, s2 = 0.f;
  for (int i = threadIdx.x; i < 16 * N_ / 16; i += 256) {   // 2304 float4 per quarter
    const float4 v = ((const float4*)p)[i];
    s  += v.x + v.y + v.z + v.w;
    s2 += v.x * v.x + v.y * v.y + v.z * v.z + v.w * v.w;
  }
  #pragma unroll
  for (int off = 32; off; off >>= 1) { s += __shfl_down(s, off); s2 += __shfl_down(s2, off); }
  __shared__ float red[8];
  if ((threadIdx.x & 63) == 0) { red[(threadIdx.x >> 6) * 2] = s; red[(threadIdx.x >> 6) * 2 + 1] = s2; }
  __syncthreads();
  if (threadIdx.x == 0) {
    float S = 0.f, S2 = 0.f;
    for (int w = 0; w < 4; w++) { S += red[w * 2]; S2 += red[w * 2 + 1]; }
    part[blockIdx.x] = make_float2(S, S2);
  }
}

// ---------------- GN apply + transpose -> xnT[b][n][c] bf16 ----------------
__global__ __launch_bounds__(256) void gn_apply_t(
    const float* __restrict__ x, const float2* __restrict__ part,
    const float* __restrict__ gamma, const float* __restrict__ beta,
    u16* __restrict__ xnT) {
  __shared__ u16 T[64][72];
  const int c0 = blockIdx.x * 64, n0 = blockIdx.y * 64, b = blockIdx.z;
  const int r = threadIdx.x >> 2, ch = (threadIdx.x & 3) * 16;
  const int cc = c0 + r;
  const float2* pp = part + (size_t)(b * G_ + (cc >> 4)) * 4;
  const float S  = pp[0].x + pp[1].x + pp[2].x + pp[3].x;
  const float S2 = pp[0].y + pp[1].y + pp[2].y + pp[3].y;
  const float inv = 1.f / (16.f * N_);
  const float mean = S * inv;
  const float rstd = rsqrtf(S2 * inv - mean * mean + 1e-5f);
  const float sc = rstd * gamma[cc];
  const float sh = beta[cc] - mean * sc;
  const float* src = x + (size_t)(b * C_ + cc) * N_ + n0 + ch;
  #pragma unroll
  for (int j = 0; j < 16; j += 4) {
    const float4 v = *(const float4*)(src + j);
    us4 o; o[0] = f2bf(v.x * sc + sh); o[1] = f2bf(v.y * sc + sh);
    o[2] = f2bf(v.z * sc + sh); o[3] = f2bf(v.w * sc + sh);
    *(us4*)&T[r][ch + j] = o;
  }
  __syncthreads();
  us8 o1, o2;
  #pragma unroll
  for (int j = 0; j < 8; j++) { o1[j] = T[ch + j][r]; o2[j] = T[ch + 8 + j][r]; }
  u16* dst = xnT + (size_t)(b * N_ + n0 + r) * C_ + c0 + ch;
  *(us8*)dst = o1;
  *(us8*)(dst + 8) = o2;
}

// ---------------- GEMM: C[bz][m][n] = A[m][k] * B[bz][n][k]^T (A,B bf16) ----------------
// m97 structure: linear LDS [128][32], global_load_lds width-16 staging, 2 barriers/k-step.
// MODE 2 (qkv): epilogue scatters q->qT, k->kT ([b][h][n][d]), v->vsec
//   (d-major, n-PERMUTED within each 64-col group so attn PV b-frag is one b128).
// MODE 1 (out proj): f32 output + bias.
template <int MODE>
__global__ __launch_bounds__(256) void gemm_bf16(
    const u16* __restrict__ A, const u16* __restrict__ Bb16,
    void* __restrict__ C, const float* __restrict__ bias,
    u16* __restrict__ qT, u16* __restrict__ kT, u16* __restrict__ vout,
    const int M, const int N, const int K) {
  __shared__ u16 As[128][32];
  __shared__ u16 Bs[128][32];
  const int tid = threadIdx.x;
  const int wave = tid >> 6, lane = tid & 63;
  const int l16 = lane & 15, lq = lane >> 4;
  const int m0 = blockIdx.x * 128, n0 = blockIdx.y * 128, bz = blockIdx.z;
  const int wm = (wave >> 1) * 64, wn = (wave & 1) * 64;
  const u16* Bb = Bb16 + (size_t)bz * N * K;

  f32x4 acc[4][4];
  #pragma unroll
  for (int mi = 0; mi < 4; mi++)
    #pragma unroll
    for (int ni = 0; ni < 4; ni++) {
      acc[mi][ni][0] = 0.f; acc[mi][ni][1] = 0.f; acc[mi][ni][2] = 0.f; acc[mi][ni][3] = 0.f;
    }

  const int grow = wave * 32 + (lane >> 2);   // global row this lane fetches (first shot)
  const int gcol = (lane & 3) * 8;            // u16 col offset
  for (int kt = 0; kt < K; kt += 32) {
    __syncthreads();
    gload16(&A[(size_t)(m0 + grow) * K + kt + gcol],      &As[wave * 32][0]);
    gload16(&A[(size_t)(m0 + grow + 16) * K + kt + gcol], &As[wave * 32 + 16][0]);
    gload16(&Bb[(size_t)(n0 + grow) * K + kt + gcol],      &Bs[wave * 32][0]);
    gload16(&Bb[(size_t)(n0 + grow + 16) * K + kt + gcol], &Bs[wave * 32 + 16][0]);
    __syncthreads();
    bf16x8 af[4], bfr[4];
    #pragma unroll
    for (int mi = 0; mi < 4; mi++) af[mi] = *(const bf16x8*)&As[wm + mi * 16 + l16][lq * 8];
    #pragma unroll
    for (int ni = 0; ni < 4; ni++) bfr[ni] = *(const bf16x8*)&Bs[wn + ni * 16 + l16][lq * 8];
    #pragma unroll
    for (int mi = 0; mi < 4; mi++)
      #pragma unroll
      for (int ni = 0; ni < 4; ni++)
        acc[mi][ni] = __builtin_amdgcn_mfma_f32_16x16x32_bf16(af[mi], bfr[ni], acc[mi][ni], 0, 0, 0);
  }
  #pragma unroll
  for (int mi = 0; mi < 4; mi++) {
    const int row0 = m0 + wm + mi * 16 + lq * 4;
    #pragma unroll
    for (int ni = 0; ni < 4; ni++) {
      const int col = n0 + wn + ni * 16 + l16;
      if (MODE == 1) {
        #pragma unroll
        for (int j = 0; j < 4; j++) {
          const size_t idx = ((size_t)bz * M + row0 + j) * N + col;
          ((float*)C)[idx] = acc[mi][ni][j] + bias[row0 + j];
        }
      } else {
        const int which = row0 >> 9;           // 0=q, 1=k, 2=v
        if (which < 2) {
          const int h = (row0 >> 6) & 7, d0 = row0 & 63;
          u16* dst = which ? kT : qT;
          us4 o;
          #pragma unroll
          for (int j = 0; j < 4; j++) o[j] = f2bf(acc[mi][ni][j]);
          *(us4*)&dst[((size_t)((bz * H_ + h) * N_) + col) * D_ + d0] = o;
        } else {
          // n-permute within 64-group: n = g32 + hi*16 + lq2*4 + j -> g32 + lq2*8 + hi*4 + j
          const int cp = (col & ~63) | (col & 32) | (((col >> 2) & 3) << 3) |
                         (((col >> 4) & 1) << 2) | (col & 3);
          #pragma unroll
          for (int j = 0; j < 4; j++)
            vout[((size_t)(bz * 512) + (row0 & 511) + j) * N + cp] = f2bf(acc[mi][ni][j]);
        }
      }
    }
  }
}

// ---------------- flash attention v17: 32 q-rows/wave (fragment reuse), SPLIT=4 ----------------
// block = (h, q-tile of 256, b*SPLIT+sp), 8 waves x 32 q-rows, 9 k-tiles.
// Each K/V b128 fragment read feeds TWO MFMAs (qi=0,1) -> LDS read traffic halved
// vs 16-q/wave. VGPR ~52 (8 waves/SIMD); grid 1152 = 4.5 blocks/CU, 4 resident.
// gload16 staging with XOR swizzle on the GLOBAL source chunk (linear LDS dest);
// V n-permuted in global (gemm1 epilogue) so PV b-frag is one b128 read.
__global__ __launch_bounds__(512) void attn_kernel17(
    const u16* __restrict__ qT, const u16* __restrict__ kT,
    const u16* __restrict__ vp, u16* __restrict__ po0,
    float* __restrict__ pl) {
  __shared__ u16 Ks[2][64][64];
  __shared__ u16 Vs[2][64][64];

  const int h = blockIdx.x;
  const int b = blockIdx.z >> 2, sp = blockIdx.z & 3;
  const int q0 = blockIdx.y * 256;
  const int tid = threadIdx.x;
  const int wave = tid >> 6, lane = tid & 63;
  const int l16 = lane & 15, lq = lane >> 4;
  const int h3 = l16 & 7;                  // read-side XOR key
  const int kt0 = sp * NT;

  // Q fragments (B-operand: lane row = q_local = l16), 32 rows per wave (qi=0,1)
  bf16x8 qf[2][2];
  {
    const u16* qb = qT + ((size_t)((b * H_ + h) * N_ + q0 + wave * 32)) * D_;
    #pragma unroll
    for (int qi = 0; qi < 2; qi++)
      #pragma unroll
      for (int dh = 0; dh < 2; dh++)
        qf[qi][dh] = *(const bf16x8*)(qb + (size_t)(qi * 16 + l16) * D_ + dh * 32 + lq * 8);
  }

  float l[2] = {0.f, 0.f};
  f32x4 acc[2][4];
  #pragma unroll
  for (int qi = 0; qi < 2; qi++)
    #pragma unroll
    for (int di = 0; di < 4; di++) {
      acc[qi][di][0] = 0.f; acc[qi][di][1] = 0.f; acc[qi][di][2] = 0.f; acc[qi][di][3] = 0.f;
    }
  const f32x4 z4 = {0.f, 0.f, 0.f, 0.f};

  const u16* kbase = kT + (size_t)(b * H_ + h) * N_ * D_;
  const u16* vbase = vp + ((size_t)(b * 512) + h * D_) * N_;
  // staging: wave w covers rows w*8..w*8+7 of the 64x64 tile (1KB per issue).
  const int srow = wave * 8 + (lane >> 3);
  const int scg  = (((lane & 7) ^ (srow & 7))) * 8;   // pre-swizzled global chunk

  // prologue: stage tile kt0 into buffer 0
  gload16(&kbase[(size_t)(kt0 * 64 + srow) * D_ + scg], &Ks[0][wave * 8][0]);
  gload16(&vbase[(size_t)srow * N_ + kt0 * 64 + scg],   &Vs[0][wave * 8][0]);

  int cur = 0;
  for (int t = 0; t < NT; t++) {
    const int kt = kt0 + t;
    __syncthreads();   // drains vmcnt -> tile t resident; prior reads of buf cur^1 done

    if (t + 1 < NT) {
      gload16(&kbase[(size_t)((kt + 1) * 64 + srow) * D_ + scg], &Ks[cur ^ 1][wave * 8][0]);
      gload16(&vbase[(size_t)srow * N_ + (kt + 1) * 64 + scg],   &Vs[cur ^ 1][wave * 8][0]);
    }

    // ---- S^T = K Q^T (each K frag feeds both qi) ----
    f32x4 s[2][4];
    __builtin_amdgcn_s_setprio(1);
    #pragma unroll
    for (int ni = 0; ni < 4; ni++) {
      const bf16x8 k0 = *(const bf16x8*)&Ks[cur][ni * 16 + l16][(lq ^ h3) * 8];
      const bf16x8 k1 = *(const bf16x8*)&Ks[cur][ni * 16 + l16][((4 | lq) ^ h3) * 8];
      #pragma unroll
      for (int qi = 0; qi < 2; qi++) {
        s[qi][ni] = __builtin_amdgcn_mfma_f32_16x16x32_bf16(k0, qf[qi][0], z4, 0, 0, 0);
        s[qi][ni] = __builtin_amdgcn_mfma_f32_16x16x32_bf16(k1, qf[qi][1], s[qi][ni], 0, 0, 0);
      }
    }
    __builtin_amdgcn_s_setprio(0);

    // ---- p = exp2(s); l in-lane; pack directly into PV a-frag words ----
    union { u32 w[4]; bf16x8 v; } af[2][2];   // [qi][kh]
    #pragma unroll
    for (int qi = 0; qi < 2; qi++) {
      float rs = 0.f;
      #pragma unroll
      for (int ni = 0; ni < 4; ni++) {
        const float p0 = __builtin_amdgcn_exp2f(s[qi][ni][0]);
        const float p1 = __builtin_amdgcn_exp2f(s[qi][ni][1]);
        const float p2 = __builtin_amdgcn_exp2f(s[qi][ni][2]);
        const float p3 = __builtin_amdgcn_exp2f(s[qi][ni][3]);
        rs += (p0 + p1) + (p2 + p3);
        af[qi][ni >> 1].w[(ni & 1) * 2]     = pack2bf(p0, p1);
        af[qi][ni >> 1].w[(ni & 1) * 2 + 1] = pack2bf(p2, p3);
      }
      l[qi] += rs;
    }

    // ---- PV: each V frag feeds both qi ----
    __builtin_amdgcn_s_setprio(1);
    #pragma unroll
    for (int kh = 0; kh < 2; kh++)
      #pragma unroll
      for (int di = 0; di < 4; di++) {
        const bf16x8 vf = *(const bf16x8*)&Vs[cur][di * 16 + l16][(((kh << 2) | lq) ^ h3) * 8];
        #pragma unroll
        for (int qi = 0; qi < 2; qi++)
          acc[qi][di] = __builtin_amdgcn_mfma_f32_16x16x32_bf16(af[qi][kh].v, vf, acc[qi][di], 0, 0, 0);
      }
    __builtin_amdgcn_s_setprio(0);

    cur ^= 1;
  }

  // ---- epilogue: write unnormalized partial O (bf16) + partial l ----
  u16* po = po0 + (size_t)sp * ((size_t)B_ * N_ * 512);
  #pragma unroll
  for (int qi = 0; qi < 2; qi++) {
    l[qi] += __shfl_xor(l[qi], 16);
    l[qi] += __shfl_xor(l[qi], 32);
  }
  if (lq == 0) {
    #pragma unroll
    for (int qi = 0; qi < 2; qi++) {
      const int n = q0 + wave * 32 + qi * 16 + l16;
      pl[((size_t)((sp * B_ + b) * H_) + h) * N_ + n] = l[qi];
    }
  }
  #pragma unroll
  for (int qi = 0; qi < 2; qi++)
    #pragma unroll
    for (int di = 0; di < 4; di++)
      #pragma unroll
      for (int j = 0; j < 4; j++) {
        const int n = q0 + wave * 32 + qi * 16 + lq * 4 + j;
        po[((size_t)(b * N_) + n) * 512 + h * D_ + di * 16 + l16] = f2bf(acc[qi][di][j]);
      }
}

// ---------------- combine: innerT = (sum_sp po_sp) / (sum_sp pl_sp), bf16 ----------------
__global__ __launch_bounds__(256) void combine_norm(
    const u16* __restrict__ po0, const float* __restrict__ pl,
    u16* __restrict__ innerT) {
  const int bn = blockIdx.x * 4 + (threadIdx.x >> 6);   // b*N + n
  const int b = bn / N_, n = bn - b * N_;
  const int c0 = (threadIdx.x & 63) * 8;
  const int h = c0 >> 6;
  const size_t lidx = ((size_t)(b * H_) + h) * N_ + n;
  const size_t lstr = (size_t)B_ * H_ * N_;
  const float rl = 1.0f / (pl[lidx] + pl[lidx + lstr] + pl[lidx + 2 * lstr] + pl[lidx + 3 * lstr]);
  const size_t base = (size_t)bn * 512 + c0;
  const size_t pstr = (size_t)B_ * N_ * 512;
  const us8 a0 = *(const us8*)&po0[base];
  const us8 a1 = *(const us8*)&po0[base + pstr];
  const us8 a2 = *(const us8*)&po0[base + 2 * pstr];
  const us8 a3 = *(const us8*)&po0[base + 3 * pstr];
  us8 o;
  #pragma unroll
  for (int j = 0; j < 8; j++)
    o[j] = f2bf((bf2f(a0[j]) + bf2f(a1[j]) + bf2f(a2[j]) + bf2f(a3[j])) * rl);
  *(us8*)&innerT[base] = o;
}

extern "C" void kernel_launch(void* const* d_in, const int* in_sizes, int n_in,
                              void* d_out, int out_size, void* d_ws, size_t ws_size,
                              hipStream_t stream) {
  const float* x     = (const float*)d_in[0];
  const float* gamma = (const float*)d_in[1];
  const float* beta  = (const float*)d_in[2];
  const float* w_qkv = (const float*)d_in[3];
  const float* w_out = (const float*)d_in[4];
  const float* b_out = (const float*)d_in[5];
  float* out = (float*)d_out;

  char* ws = (char*)d_ws;
  u16*    xnT    = (u16*)(ws + 0);          // gemm1 B input; dead after gemm1
  u16*    wq_bf  = (u16*)(ws + 9437184);    // dead after gemm1
  u16*    po0    = (u16*)(ws + 0);          // 4 partials @ 0,9.44,18.87,28.31 MB (during attn)
  u16*    vsec   = (u16*)(ws + 37748736);
  u16*    qT     = (u16*)(ws + 47185920);   // innerT after attn (qT dead)
  u16*    kT     = (u16*)(ws + 56623104);
  float*  pl     = (float*)(ws + 66060288);
  float2* part   = (float2*)(ws + 67239936);
  u16*    wo_bf  = (u16*)(ws + 67244032);
  u16*    innerT = qT;                      // alias; qT dead after attn

  cast_weights<<<dim3(256), dim3(256), 0, stream>>>(w_qkv, w_out, wq_bf, wo_bf);
  gn_stats_part<<<dim3(B_ * G_ * 4), dim3(256), 0, stream>>>(x, part);
  gn_apply_t<<<dim3(C_ / 64, N_ / 64, B_), dim3(256), 0, stream>>>(x, part, gamma, beta, xnT);
  gemm_bf16<2><<<dim3(12, 18, B_), dim3(256), 0, stream>>>(
      wq_bf, xnT, nullptr, nullptr, qT, kT, vsec, 1536, N_, C_);
  attn_kernel17<<<dim3(H_, N_ / 256, B_ * SPLIT), dim3(512), 0, stream>>>(qT, kT, vsec, po0, pl);
  combine_norm<<<dim3(B_ * N_ / 4), dim3(256), 0, stream>>>(po0, pl, innerT);
  gemm_bf16<1><<<dim3(4, 18, B_), dim3(256), 0, stream>>>(
      wo_bf, innerT, (void*)out, b_out, nullptr, nullptr, nullptr, C_, N_, C_);
}

// Round 18
// 129.509 us; speedup vs baseline: 1.1128x; 1.0692x over previous
//
#include <hip/hip_runtime.h>
#include <hip/hip_bf16.h>

// SelfAttention fused pipeline, bf16 MFMA path, K-split flash attention.
// x[4,512,48,48] -> GN(32) -> qkv 1x1 conv -> 8-head attn (N=2304,D=64) -> out proj.
//
// ws layout (67.18 MB < 68.16 MB proven safe):
//   innerT[4][2304][512] bf16 @ 0          (aliases xnT; xnT dead after gemm1)
//   wq_bf [1536][512] bf16    @ 9437184
//   po0   [4][2304][512] bf16 @ 11010048   (unnormalized partial O, split 0)
//   po1   [4][2304][512] bf16 @ 20447232   (split 1)
//   vsec  [4][512][2304] bf16 @ 37748736   (d-major, n-PERMUTED per 64-group)
//   qT    [4][8][2304][64] bf16 @ 47185920 (QSCALE folded at cast)
//   kT    [4][8][2304][64] bf16 @ 56623104
//   pl    [2][4][8][2304] f32  @ 66060288
//   part  [128][4] float2      @ 66650112  (GN partial sums)
//   wo_bf [512][512] bf16      @ 66655232

typedef unsigned short u16;
typedef unsigned int u32;
typedef __attribute__((ext_vector_type(8))) short bf16x8;
typedef __attribute__((ext_vector_type(4))) float f32x4;
typedef __attribute__((ext_vector_type(8))) unsigned short us8;
typedef __attribute__((ext_vector_type(4))) unsigned short us4;

#define B_ 4
#define C_ 512
#define N_ 2304
#define H_ 8
#define D_ 64
#define G_ 32
#define SPLIT 2
#define NT (N_ / 64 / SPLIT)   // 18 k-tiles per split block

// log2(e)/8: folded into W_q at cast so QK^T lands in exp2 domain.
#define QSCALE 0.1803368801111204f
// No max subtraction: exp2-domain scores |s| <~ 12, exp2(s) <= ~4096 fits f32/bf16;
// softmax is shift-invariant.

__device__ __forceinline__ u16 f2bf(float f) {
  unsigned u = __float_as_uint(f);
  u += 0x7FFFu + ((u >> 16) & 1u);   // RNE
  return (u16)(u >> 16);
}
__device__ __forceinline__ float bf2f(u16 h) {
  return __uint_as_float(((unsigned)h) << 16);
}
__device__ __forceinline__ u32 pack2bf(float lo, float hi) {
  __hip_bfloat162 t = __float22bfloat162_rn(float2{lo, hi});
  u32 r;
  __builtin_memcpy(&r, &t, 4);
  return r;
}

// async global->LDS, 16B per lane. LDS dest = wave-uniform base + lane*16.
__device__ __forceinline__ void gload16(const void* g, void* l) {
  __builtin_amdgcn_global_load_lds(
      reinterpret_cast<const __attribute__((address_space(1))) unsigned int*>(
          reinterpret_cast<unsigned long long>(g)),
      reinterpret_cast<__attribute__((address_space(3))) unsigned int*>(
          static_cast<unsigned int>(reinterpret_cast<unsigned long long>(l))),
      16, 0, 0);
}

// ---------------- weight cast (q rows pre-scaled by QSCALE) ----------------
__global__ __launch_bounds__(256) void cast_weights(
    const float* __restrict__ wq, const float* __restrict__ wo,
    u16* __restrict__ wq_bf, u16* __restrict__ wo_bf) {
  const int n1 = 1536 * 512 / 4, n2 = 512 * 512 / 4;
  const int nq = 512 * 512 / 4;   // q section in float4 units
  for (int i = blockIdx.x * 256 + threadIdx.x; i < n1 + n2; i += gridDim.x * 256) {
    const float4 v = (i < n1) ? ((const float4*)wq)[i] : ((const float4*)wo)[i - n1];
    const float sc = (i < nq) ? QSCALE : 1.0f;
    us4 o; o[0] = f2bf(v.x * sc); o[1] = f2bf(v.y * sc); o[2] = f2bf(v.z * sc); o[3] = f2bf(v.w * sc);
    if (i < n1) ((us4*)wq_bf)[i] = o; else ((us4*)wo_bf)[i - n1] = o;
  }
}

// ---------------- GN partial sums: 4 blocks per (b,g), deterministic ----------------
__global__ __launch_bounds__(256) void gn_stats_part(const float* __restrict__ x,
                                                     float2* __restrict__ part) {
  const int bg = blockIdx.x >> 2, q = blockIdx.x & 3;
  const float* p = x + (size_t)bg * 16 * N_ + (size_t)q * (16 * N_ / 4);
  float s = 0.f, s2 = 0.f;
  for (int i = threadIdx.x; i < 16 * N_ / 16; i += 256) {   // 2304 float4 per quarter
    const float4 v = ((const float4*)p)[i];
    s  += v.x + v.y + v.z + v.w;
    s2 += v.x * v.x + v.y * v.y + v.z * v.z + v.w * v.w;
  }
  #pragma unroll
  for (int off = 32; off; off >>= 1) { s += __shfl_down(s, off); s2 += __shfl_down(s2, off); }
  __shared__ float red[8];
  if ((threadIdx.x & 63) == 0) { red[(threadIdx.x >> 6) * 2] = s; red[(threadIdx.x >> 6) * 2 + 1] = s2; }
  __syncthreads();
  if (threadIdx.x == 0) {
    float S = 0.f, S2 = 0.f;
    for (int w = 0; w < 4; w++) { S += red[w * 2]; S2 += red[w * 2 + 1]; }
    part[blockIdx.x] = make_float2(S, S2);
  }
}

// ---------------- GN apply + transpose -> xnT[b][n][c] bf16 ----------------
__global__ __launch_bounds__(256) void gn_apply_t(
    const float* __restrict__ x, const float2* __restrict__ part,
    const float* __restrict__ gamma, const float* __restrict__ beta,
    u16* __restrict__ xnT) {
  __shared__ u16 T[64][72];
  const int c0 = blockIdx.x * 64, n0 = blockIdx.y * 64, b = blockIdx.z;
  const int r = threadIdx.x >> 2, ch = (threadIdx.x & 3) * 16;
  const int cc = c0 + r;
  const float2* pp = part + (size_t)(b * G_ + (cc >> 4)) * 4;
  const float S  = pp[0].x + pp[1].x + pp[2].x + pp[3].x;
  const float S2 = pp[0].y + pp[1].y + pp[2].y + pp[3].y;
  const float inv = 1.f / (16.f * N_);
  const float mean = S * inv;
  const float rstd = rsqrtf(S2 * inv - mean * mean + 1e-5f);
  const float sc = rstd * gamma[cc];
  const float sh = beta[cc] - mean * sc;
  const float* src = x + (size_t)(b * C_ + cc) * N_ + n0 + ch;
  #pragma unroll
  for (int j = 0; j < 16; j += 4) {
    const float4 v = *(const float4*)(src + j);
    us4 o; o[0] = f2bf(v.x * sc + sh); o[1] = f2bf(v.y * sc + sh);
    o[2] = f2bf(v.z * sc + sh); o[3] = f2bf(v.w * sc + sh);
    *(us4*)&T[r][ch + j] = o;
  }
  __syncthreads();
  us8 o1, o2;
  #pragma unroll
  for (int j = 0; j < 8; j++) { o1[j] = T[ch + j][r]; o2[j] = T[ch + 8 + j][r]; }
  u16* dst = xnT + (size_t)(b * N_ + n0 + r) * C_ + c0 + ch;
  *(us8*)dst = o1;
  *(us8*)(dst + 8) = o2;
}

// ---------------- GEMM: C[bz][m][n] = A[m][k] * B[bz][n][k]^T (A,B bf16) ----------------
// BK=64 (8 k-steps at K=512, half the barriers), LDS [128][64] with XOR swizzle:
// 16B chunk c of row r lives at chunk c^(r&7); staging pre-swizzles the GLOBAL
// source so global_load_lds (linear dest) lands swizzled; fragment reads XOR back.
// Block index XCD-chunk swizzled (bijective; grid sizes divisible by 8).
// MODE 2 (qkv): epilogue scatters q->qT, k->kT ([b][h][n][d]), v->vsec
//   (d-major, n-PERMUTED within each 64-col group so attn PV b-frag is one b128).
// MODE 1 (out proj): f32 output + bias.
template <int MODE>
__global__ __launch_bounds__(256) void gemm_bf16(
    const u16* __restrict__ A, const u16* __restrict__ Bb16,
    void* __restrict__ C, const float* __restrict__ bias,
    u16* __restrict__ qT, u16* __restrict__ kT, u16* __restrict__ vout,
    const int M, const int N, const int K) {
  __shared__ u16 As[128][64];
  __shared__ u16 Bs[128][64];
  const int tid = threadIdx.x;
  const int wave = tid >> 6, lane = tid & 63;
  const int l16 = lane & 15, lq = lane >> 4;

  // XCD-chunked bijective block swizzle: each XCD gets a contiguous block range.
  const int gx = gridDim.x, gy = gridDim.y;
  const int lin = blockIdx.x + gx * (blockIdx.y + gy * blockIdx.z);
  const int per = (gx * gy * gridDim.z) >> 3;
  const int eff = (lin & 7) * per + (lin >> 3);
  const int m0 = (eff % gx) * 128;
  const int n0 = ((eff / gx) % gy) * 128;
  const int bz = eff / (gx * gy);

  const int wm = (wave >> 1) * 64, wn = (wave & 1) * 64;
  const u16* Bb = Bb16 + (size_t)bz * N * K;

  f32x4 acc[4][4];
  #pragma unroll
  for (int mi = 0; mi < 4; mi++)
    #pragma unroll
    for (int ni = 0; ni < 4; ni++) {
      acc[mi][ni][0] = 0.f; acc[mi][ni][1] = 0.f; acc[mi][ni][2] = 0.f; acc[mi][ni][3] = 0.f;
    }

  // staging: wave w, issue j covers rows w*8 + j*32 .. +7 (1KB per issue);
  // lane's global chunk pre-swizzled so linear LDS == XOR-swizzled layout.
  const int h3r = lane >> 3;                         // row-within-8 this lane covers
  const int scg = ((lane & 7) ^ h3r) * 8;            // u16 col offset in tile (XOR key = row&7)
  const int rdx = l16 & 7;                           // read-side XOR key
  for (int kt = 0; kt < K; kt += 64) {
    __syncthreads();
    #pragma unroll
    for (int j = 0; j < 4; j++) {
      const int row = wave * 8 + j * 32 + h3r;       // (row & 7) == h3r
      gload16(&A[(size_t)(m0 + row) * K + kt + scg], &As[wave * 8 + j * 32][0]);
      gload16(&Bb[(size_t)(n0 + row) * K + kt + scg], &Bs[wave * 8 + j * 32][0]);
    }
    __syncthreads();
    #pragma unroll
    for (int kk = 0; kk < 2; kk++) {
      bf16x8 af[4], bfr[4];
      #pragma unroll
      for (int mi = 0; mi < 4; mi++)
        af[mi] = *(const bf16x8*)&As[wm + mi * 16 + l16][(((kk << 2) | lq) ^ rdx) * 8];
      #pragma unroll
      for (int ni = 0; ni < 4; ni++)
        bfr[ni] = *(const bf16x8*)&Bs[wn + ni * 16 + l16][(((kk << 2) | lq) ^ rdx) * 8];
      #pragma unroll
      for (int mi = 0; mi < 4; mi++)
        #pragma unroll
        for (int ni = 0; ni < 4; ni++)
          acc[mi][ni] = __builtin_amdgcn_mfma_f32_16x16x32_bf16(af[mi], bfr[ni], acc[mi][ni], 0, 0, 0);
    }
  }
  #pragma unroll
  for (int mi = 0; mi < 4; mi++) {
    const int row0 = m0 + wm + mi * 16 + lq * 4;
    #pragma unroll
    for (int ni = 0; ni < 4; ni++) {
      const int col = n0 + wn + ni * 16 + l16;
      if (MODE == 1) {
        #pragma unroll
        for (int j = 0; j < 4; j++) {
          const size_t idx = ((size_t)bz * M + row0 + j) * N + col;
          ((float*)C)[idx] = acc[mi][ni][j] + bias[row0 + j];
        }
      } else {
        const int which = row0 >> 9;           // 0=q, 1=k, 2=v
        if (which < 2) {
          const int h = (row0 >> 6) & 7, d0 = row0 & 63;
          u16* dst = which ? kT : qT;
          us4 o;
          #pragma unroll
          for (int j = 0; j < 4; j++) o[j] = f2bf(acc[mi][ni][j]);
          *(us4*)&dst[((size_t)((bz * H_ + h) * N_) + col) * D_ + d0] = o;
        } else {
          // n-permute within 64-group: n = g32 + hi*16 + lq2*4 + j -> g32 + lq2*8 + hi*4 + j
          const int cp = (col & ~63) | (col & 32) | (((col >> 2) & 3) << 3) |
                         (((col >> 4) & 1) << 2) | (col & 3);
          #pragma unroll
          for (int j = 0; j < 4; j++)
            vout[((size_t)(bz * 512) + (row0 & 511) + j) * N + cp] = f2bf(acc[mi][ni][j]);
        }
      }
    }
  }
}

// ---------------- flash attention (r14, unchanged): global_load_lds, swizzled source ----------------
// block = (h, q-tile of 128, b*SPLIT+sp), 8 waves x 16 q-rows, 18 k-tiles.
// LDS [64][64] u16 per matrix; XOR swizzle applied to the GLOBAL source chunk with
// LINEAR LDS dest -> conflict-free staging writes and fragment reads.
// V is n-permuted in GLOBAL (gemm1 epilogue) so PV b-frag is one b128 read.
__global__ __launch_bounds__(512) void attn_kernel14(
    const u16* __restrict__ qT, const u16* __restrict__ kT,
    const u16* __restrict__ vp, u16* __restrict__ po0,
    float* __restrict__ pl) {
  __shared__ u16 Ks[2][64][64];
  __shared__ u16 Vs[2][64][64];

  const int h = blockIdx.x;
  const int b = blockIdx.z >> 1, sp = blockIdx.z & 1;
  const int q0 = blockIdx.y * 128;
  const int tid = threadIdx.x;
  const int wave = tid >> 6, lane = tid & 63;
  const int l16 = lane & 15, lq = lane >> 4;
  const int h3 = l16 & 7;                  // read-side XOR key
  const int kt0 = sp * NT;

  bf16x8 qf[2];
  {
    const u16* qb = qT + ((size_t)((b * H_ + h) * N_ + q0 + wave * 16 + l16)) * D_;
    qf[0] = *(const bf16x8*)(qb + lq * 8);
    qf[1] = *(const bf16x8*)(qb + 32 + lq * 8);
  }

  float l = 0.f;
  f32x4 acc[4];
  #pragma unroll
  for (int di = 0; di < 4; di++) {
    acc[di][0] = 0.f; acc[di][1] = 0.f; acc[di][2] = 0.f; acc[di][3] = 0.f;
  }
  const f32x4 z4 = {0.f, 0.f, 0.f, 0.f};

  const u16* kbase = kT + (size_t)(b * H_ + h) * N_ * D_;
  const u16* vbase = vp + ((size_t)(b * 512) + h * D_) * N_;
  const int srow = wave * 8 + (lane >> 3);
  const int scg  = (((lane & 7) ^ (srow & 7))) * 8;

  gload16(&kbase[(size_t)(kt0 * 64 + srow) * D_ + scg], &Ks[0][wave * 8][0]);
  gload16(&vbase[(size_t)srow * N_ + kt0 * 64 + scg],   &Vs[0][wave * 8][0]);

  int cur = 0;
  for (int t = 0; t < NT; t++) {
    const int kt = kt0 + t;
    __syncthreads();

    if (t + 1 < NT) {
      gload16(&kbase[(size_t)((kt + 1) * 64 + srow) * D_ + scg], &Ks[cur ^ 1][wave * 8][0]);
      gload16(&vbase[(size_t)srow * N_ + (kt + 1) * 64 + scg],   &Vs[cur ^ 1][wave * 8][0]);
    }

    // ---- S^T = K Q^T ----
    f32x4 s[4];
    __builtin_amdgcn_s_setprio(1);
    #pragma unroll
    for (int ni = 0; ni < 4; ni++) {
      const bf16x8 k0 = *(const bf16x8*)&Ks[cur][ni * 16 + l16][(lq ^ h3) * 8];
      const bf16x8 k1 = *(const bf16x8*)&Ks[cur][ni * 16 + l16][((4 | lq) ^ h3) * 8];
      s[ni] = __builtin_amdgcn_mfma_f32_16x16x32_bf16(k0, qf[0], z4, 0, 0, 0);
      s[ni] = __builtin_amdgcn_mfma_f32_16x16x32_bf16(k1, qf[1], s[ni], 0, 0, 0);
    }
    __builtin_amdgcn_s_setprio(0);

    // ---- p = exp2(s); l in-lane; pack directly into PV a-frag words ----
    union { u32 w[4]; bf16x8 v; } af[2];
    float rs = 0.f;
    #pragma unroll
    for (int ni = 0; ni < 4; ni++) {
      const float p0 = __builtin_amdgcn_exp2f(s[ni][0]);
      const float p1 = __builtin_amdgcn_exp2f(s[ni][1]);
      const float p2 = __builtin_amdgcn_exp2f(s[ni][2]);
      const float p3 = __builtin_amdgcn_exp2f(s[ni][3]);
      rs += (p0 + p1) + (p2 + p3);
      af[ni >> 1].w[(ni & 1) * 2]     = pack2bf(p0, p1);
      af[ni >> 1].w[(ni & 1) * 2 + 1] = pack2bf(p2, p3);
    }
    l += rs;

    // ---- PV ----
    __builtin_amdgcn_s_setprio(1);
    #pragma unroll
    for (int kh = 0; kh < 2; kh++)
      #pragma unroll
      for (int di = 0; di < 4; di++) {
        const bf16x8 vf = *(const bf16x8*)&Vs[cur][di * 16 + l16][(((kh << 2) | lq) ^ h3) * 8];
        acc[di] = __builtin_amdgcn_mfma_f32_16x16x32_bf16(af[kh].v, vf, acc[di], 0, 0, 0);
      }
    __builtin_amdgcn_s_setprio(0);

    cur ^= 1;
  }

  // ---- epilogue: write unnormalized partial O (bf16) + partial l ----
  u16* po = po0 + (size_t)sp * ((size_t)B_ * N_ * 512);
  l += __shfl_xor(l, 16);
  l += __shfl_xor(l, 32);
  if (lq == 0) {
    const int n = q0 + wave * 16 + l16;
    pl[((size_t)((sp * B_ + b) * H_) + h) * N_ + n] = l;
  }
  #pragma unroll
  for (int di = 0; di < 4; di++)
    #pragma unroll
    for (int j = 0; j < 4; j++) {
      const int n = q0 + wave * 16 + lq * 4 + j;
      po[((size_t)(b * N_) + n) * 512 + h * D_ + di * 16 + l16] = f2bf(acc[di][j]);
    }
}

// ---------------- combine: innerT = (po0+po1) * 1/(pl0+pl1), bf16 ----------------
__global__ __launch_bounds__(256) void combine_norm(
    const u16* __restrict__ po0, const u16* __restrict__ po1,
    const float* __restrict__ pl, u16* __restrict__ innerT) {
  const int bn = blockIdx.x * 4 + (threadIdx.x >> 6);   // b*N + n
  const int b = bn / N_, n = bn - b * N_;
  const int c0 = (threadIdx.x & 63) * 8;
  const int h = c0 >> 6;
  const size_t lidx = ((size_t)(b * H_) + h) * N_ + n;
  const float rl = 1.0f / (pl[lidx] + pl[lidx + (size_t)B_ * H_ * N_]);
  const size_t base = (size_t)bn * 512 + c0;
  const us8 a = *(const us8*)&po0[base];
  const us8 c = *(const us8*)&po1[base];
  us8 o;
  #pragma unroll
  for (int j = 0; j < 8; j++) o[j] = f2bf((bf2f(a[j]) + bf2f(c[j])) * rl);
  *(us8*)&innerT[base] = o;
}

extern "C" void kernel_launch(void* const* d_in, const int* in_sizes, int n_in,
                              void* d_out, int out_size, void* d_ws, size_t ws_size,
                              hipStream_t stream) {
  const float* x     = (const float*)d_in[0];
  const float* gamma = (const float*)d_in[1];
  const float* beta  = (const float*)d_in[2];
  const float* w_qkv = (const float*)d_in[3];
  const float* w_out = (const float*)d_in[4];
  const float* b_out = (const float*)d_in[5];
  float* out = (float*)d_out;

  char* ws = (char*)d_ws;
  u16*    innerT = (u16*)(ws + 0);          // also xnT before attn
  u16*    wq_bf  = (u16*)(ws + 9437184);
  u16*    po0    = (u16*)(ws + 11010048);
  u16*    po1    = (u16*)(ws + 20447232);
  u16*    vsec   = (u16*)(ws + 37748736);
  u16*    qT     = (u16*)(ws + 47185920);
  u16*    kT     = (u16*)(ws + 56623104);
  float*  pl     = (float*)(ws + 66060288);
  float2* part   = (float2*)(ws + 66650112);
  u16*    wo_bf  = (u16*)(ws + 66655232);
  u16*    xnT    = innerT;                  // alias; xnT dead after gemm1

  cast_weights<<<dim3(256), dim3(256), 0, stream>>>(w_qkv, w_out, wq_bf, wo_bf);
  gn_stats_part<<<dim3(B_ * G_ * 4), dim3(256), 0, stream>>>(x, part);
  gn_apply_t<<<dim3(C_ / 64, N_ / 64, B_), dim3(256), 0, stream>>>(x, part, gamma, beta, xnT);
  gemm_bf16<2><<<dim3(12, 18, B_), dim3(256), 0, stream>>>(
      wq_bf, xnT, nullptr, nullptr, qT, kT, vsec, 1536, N_, C_);
  attn_kernel14<<<dim3(H_, N_ / 128, B_ * SPLIT), dim3(512), 0, stream>>>(qT, kT, vsec, po0, pl);
  combine_norm<<<dim3(B_ * N_ / 4), dim3(256), 0, stream>>>(po0, po1, pl, innerT);
  gemm_bf16<1><<<dim3(4, 18, B_), dim3(256), 0, stream>>>(
      wo_bf, innerT, (void*)out, b_out, nullptr, nullptr, nullptr, C_, N_, C_);
}

// Round 20
// 126.743 us; speedup vs baseline: 1.1371x; 1.0218x over previous
//
#include <hip/hip_runtime.h>
#include <hip/hip_bf16.h>

// SelfAttention fused pipeline, bf16 MFMA path, K-split flash attention.
// x[4,512,48,48] -> GN(32) -> qkv 1x1 conv -> 8-head attn (N=2304,D=64) -> out proj.
//
// ws layout (67.18 MB < 68.16 MB proven safe):
//   innerT[4][2304][512] bf16 @ 0          (aliases xnT; xnT dead after gemm1)
//   wq_bf [1536][512] bf16    @ 9437184
//   po0   [4][2304][512] bf16 @ 11010048   (unnormalized partial O, split 0)
//   po1   [4][2304][512] bf16 @ 20447232   (split 1)
//   vsec  [4][512][2304] bf16 @ 37748736   (d-major, n-PERMUTED per 64-group)
//   qT    [4][8][2304][64] bf16 @ 47185920 (QSCALE folded at cast)
//   kT    [4][8][2304][64] bf16 @ 56623104
//   pl    [2][4][8][2304] f32  @ 66060288
//   part  [512] float2         @ 66650112  (GN partial sums: (b*32+g)*4 + quarter)
//   wo_bf [512][512] bf16      @ 66655232

typedef unsigned short u16;
typedef unsigned int u32;
typedef __attribute__((ext_vector_type(8))) short bf16x8;
typedef __attribute__((ext_vector_type(4))) float f32x4;
typedef __attribute__((ext_vector_type(8))) unsigned short us8;
typedef __attribute__((ext_vector_type(4))) unsigned short us4;

#define B_ 4
#define C_ 512
#define N_ 2304
#define H_ 8
#define D_ 64
#define G_ 32
#define SPLIT 2
#define NT (N_ / 64 / SPLIT)   // 18 k-tiles per split block

// log2(e)/8: folded into W_q at cast so QK^T lands in exp2 domain.
#define QSCALE 0.1803368801111204f
// No max subtraction: exp2-domain scores |s| <~ 12, exp2(s) <= ~4096 fits f32/bf16;
// softmax is shift-invariant.

__device__ __forceinline__ u16 f2bf(float f) {
  unsigned u = __float_as_uint(f);
  u += 0x7FFFu + ((u >> 16) & 1u);   // RNE
  return (u16)(u >> 16);
}
__device__ __forceinline__ float bf2f(u16 h) {
  return __uint_as_float(((unsigned)h) << 16);
}
__device__ __forceinline__ u32 pack2bf(float lo, float hi) {
  __hip_bfloat162 t = __float22bfloat162_rn(float2{lo, hi});
  u32 r;
  __builtin_memcpy(&r, &t, 4);
  return r;
}

// async global->LDS, 16B per lane. LDS dest = wave-uniform base + lane*16.
__device__ __forceinline__ void gload16(const void* g, void* l) {
  __builtin_amdgcn_global_load_lds(
      reinterpret_cast<const __attribute__((address_space(1))) unsigned int*>(
          reinterpret_cast<unsigned long long>(g)),
      reinterpret_cast<__attribute__((address_space(3))) unsigned int*>(
          static_cast<unsigned int>(reinterpret_cast<unsigned long long>(l))),
      16, 0, 0);
}

// ---------------- fused: weight cast (blocks 0-255) + GN partial sums (blocks 256-767) ----------------
__global__ __launch_bounds__(256) void cast_and_stats(
    const float* __restrict__ wq, const float* __restrict__ wo,
    u16* __restrict__ wq_bf, u16* __restrict__ wo_bf,
    const float* __restrict__ x, float2* __restrict__ part) {
  if (blockIdx.x < 256) {
    const int n1 = 1536 * 512 / 4, n2 = 512 * 512 / 4;
    const int nq = 512 * 512 / 4;   // q section in float4 units
    for (int i = blockIdx.x * 256 + threadIdx.x; i < n1 + n2; i += 256 * 256) {
      const float4 v = (i < n1) ? ((const float4*)wq)[i] : ((const float4*)wo)[i - n1];
      const float sc = (i < nq) ? QSCALE : 1.0f;
      us4 o; o[0] = f2bf(v.x * sc); o[1] = f2bf(v.y * sc); o[2] = f2bf(v.z * sc); o[3] = f2bf(v.w * sc);
      if (i < n1) ((us4*)wq_bf)[i] = o; else ((us4*)wo_bf)[i - n1] = o;
    }
    return;
  }
  const int bid = blockIdx.x - 256;            // 0..511 = (b*32+g)*4 + quarter
  const int bg = bid >> 2, q = bid & 3;
  const float* p = x + (size_t)bg * 16 * N_ + (size_t)q * (16 * N_ / 4);
  float s = 0.f, s2 = 0.f;
  for (int i = threadIdx.x; i < 16 * N_ / 16; i += 256) {   // 2304 float4 per quarter
    const float4 v = ((const float4*)p)[i];
    s  += v.x + v.y + v.z + v.w;
    s2 += v.x * v.x + v.y * v.y + v.z * v.z + v.w * v.w;
  }
  #pragma unroll
  for (int off = 32; off; off >>= 1) { s += __shfl_down(s, off); s2 += __shfl_down(s2, off); }
  __shared__ float red[8];
  if ((threadIdx.x & 63) == 0) { red[(threadIdx.x >> 6) * 2] = s; red[(threadIdx.x >> 6) * 2 + 1] = s2; }
  __syncthreads();
  if (threadIdx.x == 0) {
    float S = 0.f, S2 = 0.f;
    for (int w = 0; w < 4; w++) { S += red[w * 2]; S2 += red[w * 2 + 1]; }
    part[bid] = make_float2(S, S2);
  }
}

// ---------------- GN apply + transpose -> xnT[b][n][c] bf16 ----------------
__global__ __launch_bounds__(256) void gn_apply_t(
    const float* __restrict__ x, const float2* __restrict__ part,
    const float* __restrict__ gamma, const float* __restrict__ beta,
    u16* __restrict__ xnT) {
  __shared__ u16 T[64][72];
  const int c0 = blockIdx.x * 64, n0 = blockIdx.y * 64, b = blockIdx.z;
  const int r = threadIdx.x >> 2, ch = (threadIdx.x & 3) * 16;
  const int cc = c0 + r;
  const float2* pp = part + (size_t)(b * G_ + (cc >> 4)) * 4;
  const float S  = pp[0].x + pp[1].x + pp[2].x + pp[3].x;
  const float S2 = pp[0].y + pp[1].y + pp[2].y + pp[3].y;
  const float inv = 1.f / (16.f * N_);
  const float mean = S * inv;
  const float rstd = rsqrtf(S2 * inv - mean * mean + 1e-5f);
  const float sc = rstd * gamma[cc];
  const float sh = beta[cc] - mean * sc;
  const float* src = x + (size_t)(b * C_ + cc) * N_ + n0 + ch;
  #pragma unroll
  for (int j = 0; j < 16; j += 4) {
    const float4 v = *(const float4*)(src + j);
    us4 o; o[0] = f2bf(v.x * sc + sh); o[1] = f2bf(v.y * sc + sh);
    o[2] = f2bf(v.z * sc + sh); o[3] = f2bf(v.w * sc + sh);
    *(us4*)&T[r][ch + j] = o;
  }
  __syncthreads();
  us8 o1, o2;
  #pragma unroll
  for (int j = 0; j < 8; j++) { o1[j] = T[ch + j][r]; o2[j] = T[ch + 8 + j][r]; }
  u16* dst = xnT + (size_t)(b * N_ + n0 + r) * C_ + c0 + ch;
  *(us8*)dst = o1;
  *(us8*)(dst + 8) = o2;
}

// ---------------- QKV GEMM: 256x128 tile, BK=64, XOR-swizzled LDS, 512 threads ----------------
// qkv[bz][m][n] = wq_bf[m][k] * xnT[bz][n][k]^T; epilogue scatters q->qT, k->kT
// ([b][h][n][d]), v->vsec (d-major, n-PERMUTED per 64-group).
__global__ __launch_bounds__(512) void gemm_qkv(
    const u16* __restrict__ A, const u16* __restrict__ Bb16,
    u16* __restrict__ qT, u16* __restrict__ kT, u16* __restrict__ vout) {
  __shared__ u16 As[256][64];
  __shared__ u16 Bs[128][64];
  const int tid = threadIdx.x;
  const int wave = tid >> 6, lane = tid & 63;
  const int l16 = lane & 15, lq = lane >> 4;

  // XCD-chunked bijective block swizzle over grid (6,18,4) = 432 (432%8==0).
  const int lin = blockIdx.x + 6 * (blockIdx.y + 18 * blockIdx.z);
  const int per = 432 >> 3;
  const int eff = (lin & 7) * per + (lin >> 3);
  const int m0 = (eff % 6) * 256;
  const int n0 = ((eff / 6) % 18) * 128;
  const int bz = eff / 108;

  const int wm = (wave >> 1) * 64, wn = (wave & 1) * 64;
  const u16* Bb = Bb16 + (size_t)bz * N_ * C_;

  f32x4 acc[4][4];
  #pragma unroll
  for (int mi = 0; mi < 4; mi++)
    #pragma unroll
    for (int ni = 0; ni < 4; ni++) {
      acc[mi][ni][0] = 0.f; acc[mi][ni][1] = 0.f; acc[mi][ni][2] = 0.f; acc[mi][ni][3] = 0.f;
    }

  const int h3r = lane >> 3;                 // row-within-8 this lane covers
  const int scg = ((lane & 7) ^ h3r) * 8;    // pre-swizzled global chunk (u16 offset)
  const int rdx = l16 & 7;                   // read-side XOR key
  for (int kt = 0; kt < C_; kt += 64) {
    __syncthreads();
    #pragma unroll
    for (int j = 0; j < 4; j++) {
      const int row = wave * 8 + j * 64 + h3r;   // (row & 7) == h3r
      gload16(&A[(size_t)(m0 + row) * C_ + kt + scg], &As[wave * 8 + j * 64][0]);
    }
    #pragma unroll
    for (int j = 0; j < 2; j++) {
      const int row = wave * 8 + j * 64 + h3r;
      gload16(&Bb[(size_t)(n0 + row) * C_ + kt + scg], &Bs[wave * 8 + j * 64][0]);
    }
    __syncthreads();
    #pragma unroll
    for (int kk = 0; kk < 2; kk++) {
      bf16x8 af[4], bfr[4];
      #pragma unroll
      for (int mi = 0; mi < 4; mi++)
        af[mi] = *(const bf16x8*)&As[wm + mi * 16 + l16][(((kk << 2) | lq) ^ rdx) * 8];
      #pragma unroll
      for (int ni = 0; ni < 4; ni++)
        bfr[ni] = *(const bf16x8*)&Bs[wn + ni * 16 + l16][(((kk << 2) | lq) ^ rdx) * 8];
      #pragma unroll
      for (int mi = 0; mi < 4; mi++)
        #pragma unroll
        for (int ni = 0; ni < 4; ni++)
          acc[mi][ni] = __builtin_amdgcn_mfma_f32_16x16x32_bf16(af[mi], bfr[ni], acc[mi][ni], 0, 0, 0);
    }
  }
  #pragma unroll
  for (int mi = 0; mi < 4; mi++) {
    const int row0 = m0 + wm + mi * 16 + lq * 4;
    #pragma unroll
    for (int ni = 0; ni < 4; ni++) {
      const int col = n0 + wn + ni * 16 + l16;
      const int which = row0 >> 9;           // 0=q, 1=k, 2=v
      if (which < 2) {
        const int h = (row0 >> 6) & 7, d0 = row0 & 63;
        u16* dst = which ? kT : qT;
        us4 o;
        #pragma unroll
        for (int j = 0; j < 4; j++) o[j] = f2bf(acc[mi][ni][j]);
        *(us4*)&dst[((size_t)((bz * H_ + h) * N_) + col) * D_ + d0] = o;
      } else {
        // n-permute within 64-group: n = g32 + hi*16 + lq2*4 + j -> g32 + lq2*8 + hi*4 + j
        const int cp = (col & ~63) | (col & 32) | (((col >> 2) & 3) << 3) |
                       (((col >> 4) & 1) << 2) | (col & 3);
        #pragma unroll
        for (int j = 0; j < 4; j++)
          vout[((size_t)(bz * 512) + (row0 & 511) + j) * N_ + cp] = f2bf(acc[mi][ni][j]);
      }
    }
  }
}

// ---------------- out-proj GEMM: 128x128 tile, BK=64, XOR-swizzled LDS ----------------
__global__ __launch_bounds__(256) void gemm_out(
    const u16* __restrict__ A, const u16* __restrict__ Bb16,
    float* __restrict__ C, const float* __restrict__ bias,
    const int M, const int N, const int K) {
  __shared__ u16 As[128][64];
  __shared__ u16 Bs[128][64];
  const int tid = threadIdx.x;
  const int wave = tid >> 6, lane = tid & 63;
  const int l16 = lane & 15, lq = lane >> 4;

  const int gx = gridDim.x, gy = gridDim.y;
  const int lin = blockIdx.x + gx * (blockIdx.y + gy * blockIdx.z);
  const int per = (gx * gy * gridDim.z) >> 3;
  const int eff = (lin & 7) * per + (lin >> 3);
  const int m0 = (eff % gx) * 128;
  const int n0 = ((eff / gx) % gy) * 128;
  const int bz = eff / (gx * gy);

  const int wm = (wave >> 1) * 64, wn = (wave & 1) * 64;
  const u16* Bb = Bb16 + (size_t)bz * N * K;

  f32x4 acc[4][4];
  #pragma unroll
  for (int mi = 0; mi < 4; mi++)
    #pragma unroll
    for (int ni = 0; ni < 4; ni++) {
      acc[mi][ni][0] = 0.f; acc[mi][ni][1] = 0.f; acc[mi][ni][2] = 0.f; acc[mi][ni][3] = 0.f;
    }

  const int h3r = lane >> 3;
  const int scg = ((lane & 7) ^ h3r) * 8;
  const int rdx = l16 & 7;
  for (int kt = 0; kt < K; kt += 64) {
    __syncthreads();
    #pragma unroll
    for (int j = 0; j < 4; j++) {
      const int row = wave * 8 + j * 32 + h3r;
      gload16(&A[(size_t)(m0 + row) * K + kt + scg], &As[wave * 8 + j * 32][0]);
      gload16(&Bb[(size_t)(n0 + row) * K + kt + scg], &Bs[wave * 8 + j * 32][0]);
    }
    __syncthreads();
    #pragma unroll
    for (int kk = 0; kk < 2; kk++) {
      bf16x8 af[4], bfr[4];
      #pragma unroll
      for (int mi = 0; mi < 4; mi++)
        af[mi] = *(const bf16x8*)&As[wm + mi * 16 + l16][(((kk << 2) | lq) ^ rdx) * 8];
      #pragma unroll
      for (int ni = 0; ni < 4; ni++)
        bfr[ni] = *(const bf16x8*)&Bs[wn + ni * 16 + l16][(((kk << 2) | lq) ^ rdx) * 8];
      #pragma unroll
      for (int mi = 0; mi < 4; mi++)
        #pragma unroll
        for (int ni = 0; ni < 4; ni++)
          acc[mi][ni] = __builtin_amdgcn_mfma_f32_16x16x32_bf16(af[mi], bfr[ni], acc[mi][ni], 0, 0, 0);
    }
  }
  #pragma unroll
  for (int mi = 0; mi < 4; mi++) {
    const int row0 = m0 + wm + mi * 16 + lq * 4;
    #pragma unroll
    for (int ni = 0; ni < 4; ni++) {
      const int col = n0 + wn + ni * 16 + l16;
      #pragma unroll
      for (int j = 0; j < 4; j++) {
        const size_t idx = ((size_t)bz * M + row0 + j) * N + col;
        C[idx] = acc[mi][ni][j] + bias[row0 + j];
      }
    }
  }
}

// ---------------- flash attention (r14, unchanged): global_load_lds, swizzled source ----------------
__global__ __launch_bounds__(512) void attn_kernel14(
    const u16* __restrict__ qT, const u16* __restrict__ kT,
    const u16* __restrict__ vp, u16* __restrict__ po0,
    float* __restrict__ pl) {
  __shared__ u16 Ks[2][64][64];
  __shared__ u16 Vs[2][64][64];

  const int h = blockIdx.x;
  const int b = blockIdx.z >> 1, sp = blockIdx.z & 1;
  const int q0 = blockIdx.y * 128;
  const int tid = threadIdx.x;
  const int wave = tid >> 6, lane = tid & 63;
  const int l16 = lane & 15, lq = lane >> 4;
  const int h3 = l16 & 7;                  // read-side XOR key
  const int kt0 = sp * NT;

  bf16x8 qf[2];
  {
    const u16* qb = qT + ((size_t)((b * H_ + h) * N_ + q0 + wave * 16 + l16)) * D_;
    qf[0] = *(const bf16x8*)(qb + lq * 8);
    qf[1] = *(const bf16x8*)(qb + 32 + lq * 8);
  }

  float l = 0.f;
  f32x4 acc[4];
  #pragma unroll
  for (int di = 0; di < 4; di++) {
    acc[di][0] = 0.f; acc[di][1] = 0.f; acc[di][2] = 0.f; acc[di][3] = 0.f;
  }
  const f32x4 z4 = {0.f, 0.f, 0.f, 0.f};

  const u16* kbase = kT + (size_t)(b * H_ + h) * N_ * D_;
  const u16* vbase = vp + ((size_t)(b * 512) + h * D_) * N_;
  const int srow = wave * 8 + (lane >> 3);
  const int scg  = (((lane & 7) ^ (srow & 7))) * 8;

  gload16(&kbase[(size_t)(kt0 * 64 + srow) * D_ + scg], &Ks[0][wave * 8][0]);
  gload16(&vbase[(size_t)srow * N_ + kt0 * 64 + scg],   &Vs[0][wave * 8][0]);

  int cur = 0;
  for (int t = 0; t < NT; t++) {
    const int kt = kt0 + t;
    __syncthreads();

    if (t + 1 < NT) {
      gload16(&kbase[(size_t)((kt + 1) * 64 + srow) * D_ + scg], &Ks[cur ^ 1][wave * 8][0]);
      gload16(&vbase[(size_t)srow * N_ + (kt + 1) * 64 + scg],   &Vs[cur ^ 1][wave * 8][0]);
    }

    // ---- S^T = K Q^T ----
    f32x4 s[4];
    __builtin_amdgcn_s_setprio(1);
    #pragma unroll
    for (int ni = 0; ni < 4; ni++) {
      const bf16x8 k0 = *(const bf16x8*)&Ks[cur][ni * 16 + l16][(lq ^ h3) * 8];
      const bf16x8 k1 = *(const bf16x8*)&Ks[cur][ni * 16 + l16][((4 | lq) ^ h3) * 8];
      s[ni] = __builtin_amdgcn_mfma_f32_16x16x32_bf16(k0, qf[0], z4, 0, 0, 0);
      s[ni] = __builtin_amdgcn_mfma_f32_16x16x32_bf16(k1, qf[1], s[ni], 0, 0, 0);
    }
    __builtin_amdgcn_s_setprio(0);

    // ---- p = exp2(s); l in-lane; pack directly into PV a-frag words ----
    union { u32 w[4]; bf16x8 v; } af[2];
    float rs = 0.f;
    #pragma unroll
    for (int ni = 0; ni < 4; ni++) {
      const float p0 = __builtin_amdgcn_exp2f(s[ni][0]);
      const float p1 = __builtin_amdgcn_exp2f(s[ni][1]);
      const float p2 = __builtin_amdgcn_exp2f(s[ni][2]);
      const float p3 = __builtin_amdgcn_exp2f(s[ni][3]);
      rs += (p0 + p1) + (p2 + p3);
      af[ni >> 1].w[(ni & 1) * 2]     = pack2bf(p0, p1);
      af[ni >> 1].w[(ni & 1) * 2 + 1] = pack2bf(p2, p3);
    }
    l += rs;

    // ---- PV ----
    __builtin_amdgcn_s_setprio(1);
    #pragma unroll
    for (int kh = 0; kh < 2; kh++)
      #pragma unroll
      for (int di = 0; di < 4; di++) {
        const bf16x8 vf = *(const bf16x8*)&Vs[cur][di * 16 + l16][(((kh << 2) | lq) ^ h3) * 8];
        acc[di] = __builtin_amdgcn_mfma_f32_16x16x32_bf16(af[kh].v, vf, acc[di], 0, 0, 0);
      }
    __builtin_amdgcn_s_setprio(0);

    cur ^= 1;
  }

  // ---- epilogue: write unnormalized partial O (bf16) + partial l ----
  u16* po = po0 + (size_t)sp * ((size_t)B_ * N_ * 512);
  l += __shfl_xor(l, 16);
  l += __shfl_xor(l, 32);
  if (lq == 0) {
    const int n = q0 + wave * 16 + l16;
    pl[((size_t)((sp * B_ + b) * H_) + h) * N_ + n] = l;
  }
  #pragma unroll
  for (int di = 0; di < 4; di++)
    #pragma unroll
    for (int j = 0; j < 4; j++) {
      const int n = q0 + wave * 16 + lq * 4 + j;
      po[((size_t)(b * N_) + n) * 512 + h * D_ + di * 16 + l16] = f2bf(acc[di][j]);
    }
}

// ---------------- combine: innerT = (po0+po1) * 1/(pl0+pl1), bf16 ----------------
__global__ __launch_bounds__(256) void combine_norm(
    const u16* __restrict__ po0, const u16* __restrict__ po1,
    const float* __restrict__ pl, u16* __restrict__ innerT) {
  const int bn = blockIdx.x * 4 + (threadIdx.x >> 6);   // b*N + n
  const int b = bn / N_, n = bn - b * N_;
  const int c0 = (threadIdx.x & 63) * 8;
  const int h = c0 >> 6;
  const size_t lidx = ((size_t)(b * H_) + h) * N_ + n;
  const float rl = 1.0f / (pl[lidx] + pl[lidx + (size_t)B_ * H_ * N_]);
  const size_t base = (size_t)bn * 512 + c0;
  const us8 a = *(const us8*)&po0[base];
  const us8 c = *(const us8*)&po1[base];
  us8 o;
  #pragma unroll
  for (int j = 0; j < 8; j++) o[j] = f2bf((bf2f(a[j]) + bf2f(c[j])) * rl);
  *(us8*)&innerT[base] = o;
}

extern "C" void kernel_launch(void* const* d_in, const int* in_sizes, int n_in,
                              void* d_out, int out_size, void* d_ws, size_t ws_size,
                              hipStream_t stream) {
  const float* x     = (const float*)d_in[0];
  const float* gamma = (const float*)d_in[1];
  const float* beta  = (const float*)d_in[2];
  const float* w_qkv = (const float*)d_in[3];
  const float* w_out = (const float*)d_in[4];
  const float* b_out = (const float*)d_in[5];
  float* out = (float*)d_out;

  char* ws = (char*)d_ws;
  u16*    innerT = (u16*)(ws + 0);          // also xnT before attn
  u16*    wq_bf  = (u16*)(ws + 9437184);
  u16*    po0    = (u16*)(ws + 11010048);
  u16*    po1    = (u16*)(ws + 20447232);
  u16*    vsec   = (u16*)(ws + 37748736);
  u16*    qT     = (u16*)(ws + 47185920);
  u16*    kT     = (u16*)(ws + 56623104);
  float*  pl     = (float*)(ws + 66060288);
  float2* part   = (float2*)(ws + 66650112);
  u16*    wo_bf  = (u16*)(ws + 66655232);
  u16*    xnT    = innerT;                  // alias; xnT dead after gemm1

  cast_and_stats<<<dim3(768), dim3(256), 0, stream>>>(w_qkv, w_out, wq_bf, wo_bf, x, part);
  gn_apply_t<<<dim3(C_ / 64, N_ / 64, B_), dim3(256), 0, stream>>>(x, part, gamma, beta, xnT);
  gemm_qkv<<<dim3(6, 18, B_), dim3(512), 0, stream>>>(wq_bf, xnT, qT, kT, vsec);
  attn_kernel14<<<dim3(H_, N_ / 128, B_ * SPLIT), dim3(512), 0, stream>>>(qT, kT, vsec, po0, pl);
  combine_norm<<<dim3(B_ * N_ / 4), dim3(256), 0, stream>>>(po0, po1, pl, innerT);
  gemm_out<<<dim3(4, 18, B_), dim3(256), 0, stream>>>(wo_bf, innerT, out, b_out, C_, N_, C_);
}

// Round 21
// 126.418 us; speedup vs baseline: 1.1400x; 1.0026x over previous
//
#include <hip/hip_runtime.h>
#include <hip/hip_bf16.h>

// SelfAttention fused pipeline, bf16 MFMA path, K-split flash attention.
// x[4,512,48,48] -> GN(32) -> qkv 1x1 conv -> 8-head attn (N=2304,D=64) -> out proj.
// Final-norm (po0+po1)/l is fused into the out-proj GEMM's B staging.
//
// ws layout (67.18 MB < 68.16 MB proven safe):
//   xnT   [4][2304][512] bf16 @ 0          (dead after gemm_qkv)
//   wq_bf [1536][512] bf16    @ 9437184
//   po0   [4][2304][512] bf16 @ 11010048   (unnormalized partial O, split 0)
//   po1   [4][2304][512] bf16 @ 20447232   (split 1)
//   vsec  [4][512][2304] bf16 @ 37748736   (d-major, n-PERMUTED per 64-group)
//   qT    [4][8][2304][64] bf16 @ 47185920 (QSCALE folded at cast)
//   kT    [4][8][2304][64] bf16 @ 56623104
//   pl    [2][4][8][2304] f32  @ 66060288
//   part  [512] float2         @ 66650112  (GN partial sums: (b*32+g)*4 + quarter)
//   wo_bf [512][512] bf16      @ 66655232

typedef unsigned short u16;
typedef unsigned int u32;
typedef __attribute__((ext_vector_type(8))) short bf16x8;
typedef __attribute__((ext_vector_type(4))) float f32x4;
typedef __attribute__((ext_vector_type(8))) unsigned short us8;
typedef __attribute__((ext_vector_type(4))) unsigned short us4;

#define B_ 4
#define C_ 512
#define N_ 2304
#define H_ 8
#define D_ 64
#define G_ 32
#define SPLIT 2
#define NT (N_ / 64 / SPLIT)   // 18 k-tiles per split block

// log2(e)/8: folded into W_q at cast so QK^T lands in exp2 domain.
#define QSCALE 0.1803368801111204f
// No max subtraction: exp2-domain scores |s| <~ 12, exp2(s) <= ~4096 fits f32/bf16;
// softmax is shift-invariant.

__device__ __forceinline__ u16 f2bf(float f) {
  unsigned u = __float_as_uint(f);
  u += 0x7FFFu + ((u >> 16) & 1u);   // RNE
  return (u16)(u >> 16);
}
__device__ __forceinline__ float bf2f(u16 h) {
  return __uint_as_float(((unsigned)h) << 16);
}
__device__ __forceinline__ u32 pack2bf(float lo, float hi) {
  __hip_bfloat162 t = __float22bfloat162_rn(float2{lo, hi});
  u32 r;
  __builtin_memcpy(&r, &t, 4);
  return r;
}

// async global->LDS, 16B per lane. LDS dest = wave-uniform base + lane*16.
__device__ __forceinline__ void gload16(const void* g, void* l) {
  __builtin_amdgcn_global_load_lds(
      reinterpret_cast<const __attribute__((address_space(1))) unsigned int*>(
          reinterpret_cast<unsigned long long>(g)),
      reinterpret_cast<__attribute__((address_space(3))) unsigned int*>(
          static_cast<unsigned int>(reinterpret_cast<unsigned long long>(l))),
      16, 0, 0);
}

// ---------------- fused: weight cast (blocks 0-255) + GN partial sums (blocks 256-767) ----------------
__global__ __launch_bounds__(256) void cast_and_stats(
    const float* __restrict__ wq, const float* __restrict__ wo,
    u16* __restrict__ wq_bf, u16* __restrict__ wo_bf,
    const float* __restrict__ x, float2* __restrict__ part) {
  if (blockIdx.x < 256) {
    const int n1 = 1536 * 512 / 4, n2 = 512 * 512 / 4;
    const int nq = 512 * 512 / 4;   // q section in float4 units
    for (int i = blockIdx.x * 256 + threadIdx.x; i < n1 + n2; i += 256 * 256) {
      const float4 v = (i < n1) ? ((const float4*)wq)[i] : ((const float4*)wo)[i - n1];
      const float sc = (i < nq) ? QSCALE : 1.0f;
      us4 o; o[0] = f2bf(v.x * sc); o[1] = f2bf(v.y * sc); o[2] = f2bf(v.z * sc); o[3] = f2bf(v.w * sc);
      if (i < n1) ((us4*)wq_bf)[i] = o; else ((us4*)wo_bf)[i - n1] = o;
    }
    return;
  }
  const int bid = blockIdx.x - 256;            // 0..511 = (b*32+g)*4 + quarter
  const int bg = bid >> 2, q = bid & 3;
  const float* p = x + (size_t)bg * 16 * N_ + (size_t)q * (16 * N_ / 4);
  float s = 0.f, s2 = 0.f;
  for (int i = threadIdx.x; i < 16 * N_ / 16; i += 256) {   // 2304 float4 per quarter
    const float4 v = ((const float4*)p)[i];
    s  += v.x + v.y + v.z + v.w;
    s2 += v.x * v.x + v.y * v.y + v.z * v.z + v.w * v.w;
  }
  #pragma unroll
  for (int off = 32; off; off >>= 1) { s += __shfl_down(s, off); s2 += __shfl_down(s2, off); }
  __shared__ float red[8];
  if ((threadIdx.x & 63) == 0) { red[(threadIdx.x >> 6) * 2] = s; red[(threadIdx.x >> 6) * 2 + 1] = s2; }
  __syncthreads();
  if (threadIdx.x == 0) {
    float S = 0.f, S2 = 0.f;
    for (int w = 0; w < 4; w++) { S += red[w * 2]; S2 += red[w * 2 + 1]; }
    part[bid] = make_float2(S, S2);
  }
}

// ---------------- GN apply + transpose -> xnT[b][n][c] bf16 ----------------
__global__ __launch_bounds__(256) void gn_apply_t(
    const float* __restrict__ x, const float2* __restrict__ part,
    const float* __restrict__ gamma, const float* __restrict__ beta,
    u16* __restrict__ xnT) {
  __shared__ u16 T[64][72];
  const int c0 = blockIdx.x * 64, n0 = blockIdx.y * 64, b = blockIdx.z;
  const int r = threadIdx.x >> 2, ch = (threadIdx.x & 3) * 16;
  const int cc = c0 + r;
  const float2* pp = part + (size_t)(b * G_ + (cc >> 4)) * 4;
  const float S  = pp[0].x + pp[1].x + pp[2].x + pp[3].x;
  const float S2 = pp[0].y + pp[1].y + pp[2].y + pp[3].y;
  const float inv = 1.f / (16.f * N_);
  const float mean = S * inv;
  const float rstd = rsqrtf(S2 * inv - mean * mean + 1e-5f);
  const float sc = rstd * gamma[cc];
  const float sh = beta[cc] - mean * sc;
  const float* src = x + (size_t)(b * C_ + cc) * N_ + n0 + ch;
  #pragma unroll
  for (int j = 0; j < 16; j += 4) {
    const float4 v = *(const float4*)(src + j);
    us4 o; o[0] = f2bf(v.x * sc + sh); o[1] = f2bf(v.y * sc + sh);
    o[2] = f2bf(v.z * sc + sh); o[3] = f2bf(v.w * sc + sh);
    *(us4*)&T[r][ch + j] = o;
  }
  __syncthreads();
  us8 o1, o2;
  #pragma unroll
  for (int j = 0; j < 8; j++) { o1[j] = T[ch + j][r]; o2[j] = T[ch + 8 + j][r]; }
  u16* dst = xnT + (size_t)(b * N_ + n0 + r) * C_ + c0 + ch;
  *(us8*)dst = o1;
  *(us8*)(dst + 8) = o2;
}

// ---------------- QKV GEMM: 256x128 tile, BK=64, XOR-swizzled LDS, 512 threads ----------------
// qkv[bz][m][n] = wq_bf[m][k] * xnT[bz][n][k]^T; epilogue scatters q->qT, k->kT
// ([b][h][n][d]), v->vsec (d-major, n-PERMUTED per 64-group).
__global__ __launch_bounds__(512) void gemm_qkv(
    const u16* __restrict__ A, const u16* __restrict__ Bb16,
    u16* __restrict__ qT, u16* __restrict__ kT, u16* __restrict__ vout) {
  __shared__ u16 As[256][64];
  __shared__ u16 Bs[128][64];
  const int tid = threadIdx.x;
  const int wave = tid >> 6, lane = tid & 63;
  const int l16 = lane & 15, lq = lane >> 4;

  // XCD-chunked bijective block swizzle over grid (6,18,4) = 432 (432%8==0).
  const int lin = blockIdx.x + 6 * (blockIdx.y + 18 * blockIdx.z);
  const int per = 432 >> 3;
  const int eff = (lin & 7) * per + (lin >> 3);
  const int m0 = (eff % 6) * 256;
  const int n0 = ((eff / 6) % 18) * 128;
  const int bz = eff / 108;

  const int wm = (wave >> 1) * 64, wn = (wave & 1) * 64;
  const u16* Bb = Bb16 + (size_t)bz * N_ * C_;

  f32x4 acc[4][4];
  #pragma unroll
  for (int mi = 0; mi < 4; mi++)
    #pragma unroll
    for (int ni = 0; ni < 4; ni++) {
      acc[mi][ni][0] = 0.f; acc[mi][ni][1] = 0.f; acc[mi][ni][2] = 0.f; acc[mi][ni][3] = 0.f;
    }

  const int h3r = lane >> 3;                 // row-within-8 this lane covers
  const int scg = ((lane & 7) ^ h3r) * 8;    // pre-swizzled global chunk (u16 offset)
  const int rdx = l16 & 7;                   // read-side XOR key
  for (int kt = 0; kt < C_; kt += 64) {
    __syncthreads();
    #pragma unroll
    for (int j = 0; j < 4; j++) {
      const int row = wave * 8 + j * 64 + h3r;   // (row & 7) == h3r
      gload16(&A[(size_t)(m0 + row) * C_ + kt + scg], &As[wave * 8 + j * 64][0]);
    }
    #pragma unroll
    for (int j = 0; j < 2; j++) {
      const int row = wave * 8 + j * 64 + h3r;
      gload16(&Bb[(size_t)(n0 + row) * C_ + kt + scg], &Bs[wave * 8 + j * 64][0]);
    }
    __syncthreads();
    #pragma unroll
    for (int kk = 0; kk < 2; kk++) {
      bf16x8 af[4], bfr[4];
      #pragma unroll
      for (int mi = 0; mi < 4; mi++)
        af[mi] = *(const bf16x8*)&As[wm + mi * 16 + l16][(((kk << 2) | lq) ^ rdx) * 8];
      #pragma unroll
      for (int ni = 0; ni < 4; ni++)
        bfr[ni] = *(const bf16x8*)&Bs[wn + ni * 16 + l16][(((kk << 2) | lq) ^ rdx) * 8];
      #pragma unroll
      for (int mi = 0; mi < 4; mi++)
        #pragma unroll
        for (int ni = 0; ni < 4; ni++)
          acc[mi][ni] = __builtin_amdgcn_mfma_f32_16x16x32_bf16(af[mi], bfr[ni], acc[mi][ni], 0, 0, 0);
    }
  }
  #pragma unroll
  for (int mi = 0; mi < 4; mi++) {
    const int row0 = m0 + wm + mi * 16 + lq * 4;
    #pragma unroll
    for (int ni = 0; ni < 4; ni++) {
      const int col = n0 + wn + ni * 16 + l16;
      const int which = row0 >> 9;           // 0=q, 1=k, 2=v
      if (which < 2) {
        const int h = (row0 >> 6) & 7, d0 = row0 & 63;
        u16* dst = which ? kT : qT;
        us4 o;
        #pragma unroll
        for (int j = 0; j < 4; j++) o[j] = f2bf(acc[mi][ni][j]);
        *(us4*)&dst[((size_t)((bz * H_ + h) * N_) + col) * D_ + d0] = o;
      } else {
        // n-permute within 64-group: n = g32 + hi*16 + lq2*4 + j -> g32 + lq2*8 + hi*4 + j
        const int cp = (col & ~63) | (col & 32) | (((col >> 2) & 3) << 3) |
                       (((col >> 4) & 1) << 2) | (col & 3);
        #pragma unroll
        for (int j = 0; j < 4; j++)
          vout[((size_t)(bz * 512) + (row0 & 511) + j) * N_ + cp] = f2bf(acc[mi][ni][j]);
      }
    }
  }
}

// ---------------- out-proj GEMM with fused combine: B = (po0+po1)*rl staged in-kernel ----------------
// out[bz][m][n] = wo_bf[m][k] * ((po0+po1)[bz][n][k] / l[bz][n]) + bias; f32 output.
// A staged via global_load_lds (pre-swizzled source); B reg-staged: us8 po pair ->
// f32 add -> *rl -> bf16 -> ds_write_b128 at XOR-swizzled chunk (r13 pattern, 0-conflict).
__global__ __launch_bounds__(256) void gemm_out_fused(
    const u16* __restrict__ A, const u16* __restrict__ po0, const u16* __restrict__ po1,
    const float* __restrict__ pl, float* __restrict__ C, const float* __restrict__ bias) {
  __shared__ u16 As[128][64];
  __shared__ u16 Bs[128][64];
  const int tid = threadIdx.x;
  const int wave = tid >> 6, lane = tid & 63;
  const int l16 = lane & 15, lq = lane >> 4;

  // XCD-chunked bijective swizzle over grid (4,18,4) = 288 (288%8==0).
  const int lin = blockIdx.x + 4 * (blockIdx.y + 18 * blockIdx.z);
  const int per = 288 >> 3;
  const int eff = (lin & 7) * per + (lin >> 3);
  const int m0 = (eff % 4) * 128;
  const int n0 = ((eff / 4) % 18) * 128;
  const int bz = eff / 72;

  const int wm = (wave >> 1) * 64, wn = (wave & 1) * 64;

  f32x4 acc[4][4];
  #pragma unroll
  for (int mi = 0; mi < 4; mi++)
    #pragma unroll
    for (int ni = 0; ni < 4; ni++) {
      acc[mi][ni][0] = 0.f; acc[mi][ni][1] = 0.f; acc[mi][ni][2] = 0.f; acc[mi][ni][3] = 0.f;
    }

  const int h3r = lane >> 3;                 // row-within-8 this lane covers
  const int scg = ((lane & 7) ^ h3r) * 8;    // pre-swizzled global chunk for A
  const int rdx = l16 & 7;                   // read-side XOR key
  const size_t lstr = (size_t)B_ * H_ * N_;
  for (int kt = 0; kt < C_; kt += 64) {
    __syncthreads();
    // A staging: global_load_lds, pre-swizzled source
    #pragma unroll
    for (int j = 0; j < 4; j++) {
      const int row = wave * 8 + j * 32 + h3r;
      gload16(&A[(size_t)(m0 + row) * C_ + kt + scg], &As[wave * 8 + j * 32][0]);
    }
    // B staging: reg-staged combine+norm; h = kt>>6 is uniform this k-step
    #pragma unroll
    for (int j = 0; j < 4; j++) {
      const int row = wave * 8 + j * 32 + h3r;
      const size_t pbase = ((size_t)(bz * N_) + n0 + row) * 512 + kt + (lane & 7) * 8;
      const us8 a = *(const us8*)&po0[pbase];
      const us8 c2 = *(const us8*)&po1[pbase];
      const size_t lidx = ((size_t)(bz * H_) + (kt >> 6)) * N_ + n0 + row;
      const float rl = 1.0f / (pl[lidx] + pl[lidx + lstr]);
      us8 o;
      #pragma unroll
      for (int e = 0; e < 8; e++) o[e] = f2bf((bf2f(a[e]) + bf2f(c2[e])) * rl);
      *(us8*)&Bs[row][((lane & 7) ^ h3r) * 8] = o;
    }
    __syncthreads();
    #pragma unroll
    for (int kk = 0; kk < 2; kk++) {
      bf16x8 af[4], bfr[4];
      #pragma unroll
      for (int mi = 0; mi < 4; mi++)
        af[mi] = *(const bf16x8*)&As[wm + mi * 16 + l16][(((kk << 2) | lq) ^ rdx) * 8];
      #pragma unroll
      for (int ni = 0; ni < 4; ni++)
        bfr[ni] = *(const bf16x8*)&Bs[wn + ni * 16 + l16][(((kk << 2) | lq) ^ rdx) * 8];
      #pragma unroll
      for (int mi = 0; mi < 4; mi++)
        #pragma unroll
        for (int ni = 0; ni < 4; ni++)
          acc[mi][ni] = __builtin_amdgcn_mfma_f32_16x16x32_bf16(af[mi], bfr[ni], acc[mi][ni], 0, 0, 0);
    }
  }
  #pragma unroll
  for (int mi = 0; mi < 4; mi++) {
    const int row0 = m0 + wm + mi * 16 + lq * 4;
    #pragma unroll
    for (int ni = 0; ni < 4; ni++) {
      const int col = n0 + wn + ni * 16 + l16;
      #pragma unroll
      for (int j = 0; j < 4; j++) {
        const size_t idx = ((size_t)bz * C_ + row0 + j) * N_ + col;
        C[idx] = acc[mi][ni][j] + bias[row0 + j];
      }
    }
  }
}

// ---------------- flash attention (r14, unchanged): global_load_lds, swizzled source ----------------
__global__ __launch_bounds__(512) void attn_kernel14(
    const u16* __restrict__ qT, const u16* __restrict__ kT,
    const u16* __restrict__ vp, u16* __restrict__ po0,
    float* __restrict__ pl) {
  __shared__ u16 Ks[2][64][64];
  __shared__ u16 Vs[2][64][64];

  const int h = blockIdx.x;
  const int b = blockIdx.z >> 1, sp = blockIdx.z & 1;
  const int q0 = blockIdx.y * 128;
  const int tid = threadIdx.x;
  const int wave = tid >> 6, lane = tid & 63;
  const int l16 = lane & 15, lq = lane >> 4;
  const int h3 = l16 & 7;                  // read-side XOR key
  const int kt0 = sp * NT;

  bf16x8 qf[2];
  {
    const u16* qb = qT + ((size_t)((b * H_ + h) * N_ + q0 + wave * 16 + l16)) * D_;
    qf[0] = *(const bf16x8*)(qb + lq * 8);
    qf[1] = *(const bf16x8*)(qb + 32 + lq * 8);
  }

  float l = 0.f;
  f32x4 acc[4];
  #pragma unroll
  for (int di = 0; di < 4; di++) {
    acc[di][0] = 0.f; acc[di][1] = 0.f; acc[di][2] = 0.f; acc[di][3] = 0.f;
  }
  const f32x4 z4 = {0.f, 0.f, 0.f, 0.f};

  const u16* kbase = kT + (size_t)(b * H_ + h) * N_ * D_;
  const u16* vbase = vp + ((size_t)(b * 512) + h * D_) * N_;
  const int srow = wave * 8 + (lane >> 3);
  const int scg  = (((lane & 7) ^ (srow & 7))) * 8;

  gload16(&kbase[(size_t)(kt0 * 64 + srow) * D_ + scg], &Ks[0][wave * 8][0]);
  gload16(&vbase[(size_t)srow * N_ + kt0 * 64 + scg],   &Vs[0][wave * 8][0]);

  int cur = 0;
  for (int t = 0; t < NT; t++) {
    const int kt = kt0 + t;
    __syncthreads();

    if (t + 1 < NT) {
      gload16(&kbase[(size_t)((kt + 1) * 64 + srow) * D_ + scg], &Ks[cur ^ 1][wave * 8][0]);
      gload16(&vbase[(size_t)srow * N_ + (kt + 1) * 64 + scg],   &Vs[cur ^ 1][wave * 8][0]);
    }

    // ---- S^T = K Q^T ----
    f32x4 s[4];
    __builtin_amdgcn_s_setprio(1);
    #pragma unroll
    for (int ni = 0; ni < 4; ni++) {
      const bf16x8 k0 = *(const bf16x8*)&Ks[cur][ni * 16 + l16][(lq ^ h3) * 8];
      const bf16x8 k1 = *(const bf16x8*)&Ks[cur][ni * 16 + l16][((4 | lq) ^ h3) * 8];
      s[ni] = __builtin_amdgcn_mfma_f32_16x16x32_bf16(k0, qf[0], z4, 0, 0, 0);
      s[ni] = __builtin_amdgcn_mfma_f32_16x16x32_bf16(k1, qf[1], s[ni], 0, 0, 0);
    }
    __builtin_amdgcn_s_setprio(0);

    // ---- p = exp2(s); l in-lane; pack directly into PV a-frag words ----
    union { u32 w[4]; bf16x8 v; } af[2];
    float rs = 0.f;
    #pragma unroll
    for (int ni = 0; ni < 4; ni++) {
      const float p0 = __builtin_amdgcn_exp2f(s[ni][0]);
      const float p1 = __builtin_amdgcn_exp2f(s[ni][1]);
      const float p2 = __builtin_amdgcn_exp2f(s[ni][2]);
      const float p3 = __builtin_amdgcn_exp2f(s[ni][3]);
      rs += (p0 + p1) + (p2 + p3);
      af[ni >> 1].w[(ni & 1) * 2]     = pack2bf(p0, p1);
      af[ni >> 1].w[(ni & 1) * 2 + 1] = pack2bf(p2, p3);
    }
    l += rs;

    // ---- PV ----
    __builtin_amdgcn_s_setprio(1);
    #pragma unroll
    for (int kh = 0; kh < 2; kh++)
      #pragma unroll
      for (int di = 0; di < 4; di++) {
        const bf16x8 vf = *(const bf16x8*)&Vs[cur][di * 16 + l16][(((kh << 2) | lq) ^ h3) * 8];
        acc[di] = __builtin_amdgcn_mfma_f32_16x16x32_bf16(af[kh].v, vf, acc[di], 0, 0, 0);
      }
    __builtin_amdgcn_s_setprio(0);

    cur ^= 1;
  }

  // ---- epilogue: write unnormalized partial O (bf16) + partial l ----
  u16* po = po0 + (size_t)sp * ((size_t)B_ * N_ * 512);
  l += __shfl_xor(l, 16);
  l += __shfl_xor(l, 32);
  if (lq == 0) {
    const int n = q0 + wave * 16 + l16;
    pl[((size_t)((sp * B_ + b) * H_) + h) * N_ + n] = l;
  }
  #pragma unroll
  for (int di = 0; di < 4; di++)
    #pragma unroll
    for (int j = 0; j < 4; j++) {
      const int n = q0 + wave * 16 + lq * 4 + j;
      po[((size_t)(b * N_) + n) * 512 + h * D_ + di * 16 + l16] = f2bf(acc[di][j]);
    }
}

extern "C" void kernel_launch(void* const* d_in, const int* in_sizes, int n_in,
                              void* d_out, int out_size, void* d_ws, size_t ws_size,
                              hipStream_t stream) {
  const float* x     = (const float*)d_in[0];
  const float* gamma = (const float*)d_in[1];
  const float* beta  = (const float*)d_in[2];
  const float* w_qkv = (const float*)d_in[3];
  const float* w_out = (const float*)d_in[4];
  const float* b_out = (const float*)d_in[5];
  float* out = (float*)d_out;

  char* ws = (char*)d_ws;
  u16*    xnT    = (u16*)(ws + 0);          // dead after gemm_qkv
  u16*    wq_bf  = (u16*)(ws + 9437184);
  u16*    po0    = (u16*)(ws + 11010048);
  u16*    po1    = (u16*)(ws + 20447232);
  u16*    vsec   = (u16*)(ws + 37748736);
  u16*    qT     = (u16*)(ws + 47185920);
  u16*    kT     = (u16*)(ws + 56623104);
  float*  pl     = (float*)(ws + 66060288);
  float2* part   = (float2*)(ws + 66650112);
  u16*    wo_bf  = (u16*)(ws + 66655232);

  cast_and_stats<<<dim3(768), dim3(256), 0, stream>>>(w_qkv, w_out, wq_bf, wo_bf, x, part);
  gn_apply_t<<<dim3(C_ / 64, N_ / 64, B_), dim3(256), 0, stream>>>(x, part, gamma, beta, xnT);
  gemm_qkv<<<dim3(6, 18, B_), dim3(512), 0, stream>>>(wq_bf, xnT, qT, kT, vsec);
  attn_kernel14<<<dim3(H_, N_ / 128, B_ * SPLIT), dim3(512), 0, stream>>>(qT, kT, vsec, po0, pl);
  gemm_out_fused<<<dim3(4, 18, B_), dim3(256), 0, stream>>>(wo_bf, po0, po1, pl, out, b_out);
}

// Round 22
// 122.923 us; speedup vs baseline: 1.1725x; 1.0284x over previous
//
#include <hip/hip_runtime.h>
#include <hip/hip_bf16.h>

// SelfAttention fused pipeline, bf16 MFMA path, K-split flash attention.
// x[4,512,48,48] -> GN(32) -> qkv 1x1 conv -> 8-head attn (N=2304,D=64) -> out proj.
// GN folded as per-channel affine into gemm_qkv's B staging (single x pass);
// final-norm (po0+po1)/l fused into the out-proj GEMM's B staging.
//
// ws layout (67.23 MB < 68.16 MB proven safe):
//   xT    [4][2304][512] bf16 @ 0          (RAW x cast+transpose; dead after gemm_qkv)
//   wq_bf [1536][512] bf16    @ 9437184
//   po0   [4][2304][512] bf16 @ 11010048   (unnormalized partial O, split 0)
//   po1   [4][2304][512] bf16 @ 20447232   (split 1)
//   vsec  [4][512][2304] bf16 @ 37748736   (d-major, n-PERMUTED per 64-group)
//   qT    [4][8][2304][64] bf16 @ 47185920 (QSCALE folded at cast)
//   kT    [4][8][2304][64] bf16 @ 56623104
//   pl    [2][4][8][2304] f32  @ 66060288
//   part  [4][32][36] float2   @ 66650112  (GN partial sums per n-tile)
//   wo_bf [512][512] bf16      @ 66686976
//   scsh  [4][512] float2      @ 67211264  (GN affine: xn = x*sc + sh)

typedef unsigned short u16;
typedef unsigned int u32;
typedef __attribute__((ext_vector_type(8))) short bf16x8;
typedef __attribute__((ext_vector_type(4))) float f32x4;
typedef __attribute__((ext_vector_type(8))) unsigned short us8;
typedef __attribute__((ext_vector_type(4))) unsigned short us4;

#define B_ 4
#define C_ 512
#define N_ 2304
#define H_ 8
#define D_ 64
#define G_ 32
#define SPLIT 2
#define NT (N_ / 64 / SPLIT)   // 18 k-tiles per split block

// log2(e)/8: folded into W_q at cast so QK^T lands in exp2 domain.
#define QSCALE 0.1803368801111204f
// No max subtraction: exp2-domain scores |s| <~ 12, exp2(s) <= ~4096 fits f32/bf16;
// softmax is shift-invariant.

__device__ __forceinline__ u16 f2bf(float f) {
  unsigned u = __float_as_uint(f);
  u += 0x7FFFu + ((u >> 16) & 1u);   // RNE
  return (u16)(u >> 16);
}
__device__ __forceinline__ float bf2f(u16 h) {
  return __uint_as_float(((unsigned)h) << 16);
}
__device__ __forceinline__ u32 pack2bf(float lo, float hi) {
  __hip_bfloat162 t = __float22bfloat162_rn(float2{lo, hi});
  u32 r;
  __builtin_memcpy(&r, &t, 4);
  return r;
}

// async global->LDS, 16B per lane. LDS dest = wave-uniform base + lane*16.
__device__ __forceinline__ void gload16(const void* g, void* l) {
  __builtin_amdgcn_global_load_lds(
      reinterpret_cast<const __attribute__((address_space(1))) unsigned int*>(
          reinterpret_cast<unsigned long long>(g)),
      reinterpret_cast<__attribute__((address_space(3))) unsigned int*>(
          static_cast<unsigned int>(reinterpret_cast<unsigned long long>(l))),
      16, 0, 0);
}

// ---------------- prep: weight cast (blocks 0-255) + x cast/transpose + GN partials ----------------
// blocks 256..1407: one (c-tile 64, n-tile 64, b); wave w = group quarter ->
// wave-reduce gives partial sums for group g = c0/16 + w over this n-tile.
__global__ __launch_bounds__(256) void prep_all(
    const float* __restrict__ wq, const float* __restrict__ wo,
    u16* __restrict__ wq_bf, u16* __restrict__ wo_bf,
    const float* __restrict__ x, u16* __restrict__ xT, float2* __restrict__ part) {
  if (blockIdx.x < 256) {
    const int n1 = 1536 * 512 / 4, n2 = 512 * 512 / 4;
    const int nq = 512 * 512 / 4;   // q section in float4 units
    for (int i = blockIdx.x * 256 + threadIdx.x; i < n1 + n2; i += 256 * 256) {
      const float4 v = (i < n1) ? ((const float4*)wq)[i] : ((const float4*)wo)[i - n1];
      const float sc = (i < nq) ? QSCALE : 1.0f;
      us4 o; o[0] = f2bf(v.x * sc); o[1] = f2bf(v.y * sc); o[2] = f2bf(v.z * sc); o[3] = f2bf(v.w * sc);
      if (i < n1) ((us4*)wq_bf)[i] = o; else ((us4*)wo_bf)[i - n1] = o;
    }
    return;
  }
  __shared__ u16 T[64][72];
  const int bid = blockIdx.x - 256;            // 0..1151
  const int b = bid / 288, rem = bid % 288;
  const int c0 = (rem & 7) * 64, ni = rem >> 3;   // ni = n-tile 0..35
  const int n0 = ni * 64;
  const int tid = threadIdx.x;
  const int r = tid >> 2, ch = (tid & 3) * 16;
  const float* src = x + (size_t)(b * C_ + c0 + r) * N_ + n0 + ch;
  float s = 0.f, s2 = 0.f;
  #pragma unroll
  for (int j = 0; j < 16; j += 4) {
    const float4 v = *(const float4*)(src + j);
    s  += v.x + v.y + v.z + v.w;
    s2 += v.x * v.x + v.y * v.y + v.z * v.z + v.w * v.w;
    us4 o; o[0] = f2bf(v.x); o[1] = f2bf(v.y); o[2] = f2bf(v.z); o[3] = f2bf(v.w);
    *(us4*)&T[r][ch + j] = o;
  }
  // wave w = c-rows 16w..16w+15 = one group quarter; reduce across 64 lanes
  #pragma unroll
  for (int off = 32; off; off >>= 1) { s += __shfl_xor(s, off); s2 += __shfl_xor(s2, off); }
  if ((tid & 63) == 0) {
    const int g = (c0 >> 4) + (tid >> 6);
    part[((size_t)(b * G_) + g) * 36 + ni] = make_float2(s, s2);
  }
  __syncthreads();
  us8 o1, o2;
  #pragma unroll
  for (int j = 0; j < 8; j++) { o1[j] = T[ch + j][r]; o2[j] = T[ch + 8 + j][r]; }
  u16* dst = xT + (size_t)(b * N_ + n0 + r) * C_ + c0 + ch;
  *(us8*)dst = o1;
  *(us8*)(dst + 8) = o2;
}

// ---------------- finalize GN stats -> scsh[b][c] = (sc, sh) ----------------
__global__ __launch_bounds__(512) void make_scsh(
    const float2* __restrict__ part, const float* __restrict__ gamma,
    const float* __restrict__ beta, float2* __restrict__ scsh) {
  const int b = blockIdx.x, c = threadIdx.x;
  const float2* pp = part + (size_t)(b * G_ + (c >> 4)) * 36;
  float S = 0.f, S2 = 0.f;
  #pragma unroll 4
  for (int i = 0; i < 36; i++) { S += pp[i].x; S2 += pp[i].y; }
  const float inv = 1.f / (16.f * N_);
  const float mean = S * inv;
  const float rstd = rsqrtf(S2 * inv - mean * mean + 1e-5f);
  const float sc = rstd * gamma[c];
  scsh[b * C_ + c] = make_float2(sc, beta[c] - mean * sc);
}

// ---------------- QKV GEMM: 256x128 tile, BK=64, GN affine fused in B staging ----------------
// qkv[bz][m][n] = wq_bf[m][k] * (xT[bz][n][k]*sc[bz][k]+sh[bz][k])^T; epilogue
// scatters q->qT, k->kT ([b][h][n][d]), v->vsec (d-major, n-PERMUTED per 64-group).
// A staged via global_load_lds (pre-swizzled source); B reg-staged with affine,
// ds_write_b128 at XOR-swizzled chunk (r13/r21 pattern, 0-conflict).
__global__ __launch_bounds__(512) void gemm_qkv(
    const u16* __restrict__ A, const u16* __restrict__ xT,
    const float2* __restrict__ scsh,
    u16* __restrict__ qT, u16* __restrict__ kT, u16* __restrict__ vout) {
  __shared__ u16 As[256][64];
  __shared__ u16 Bs[128][64];
  const int tid = threadIdx.x;
  const int wave = tid >> 6, lane = tid & 63;
  const int l16 = lane & 15, lq = lane >> 4;

  // XCD-chunked bijective block swizzle over grid (6,18,4) = 432 (432%8==0).
  const int lin = blockIdx.x + 6 * (blockIdx.y + 18 * blockIdx.z);
  const int per = 432 >> 3;
  const int eff = (lin & 7) * per + (lin >> 3);
  const int m0 = (eff % 6) * 256;
  const int n0 = ((eff / 6) % 18) * 128;
  const int bz = eff / 108;

  const int wm = (wave >> 1) * 64, wn = (wave & 1) * 64;
  const u16* Bb = xT + (size_t)bz * N_ * C_;
  const float2* sb = scsh + bz * C_;

  f32x4 acc[4][4];
  #pragma unroll
  for (int mi = 0; mi < 4; mi++)
    #pragma unroll
    for (int ni = 0; ni < 4; ni++) {
      acc[mi][ni][0] = 0.f; acc[mi][ni][1] = 0.f; acc[mi][ni][2] = 0.f; acc[mi][ni][3] = 0.f;
    }

  const int h3r = lane >> 3;                 // row-within-8 this lane covers
  const int scg = ((lane & 7) ^ h3r) * 8;    // pre-swizzled global chunk (A)
  const int rdx = l16 & 7;                   // read-side XOR key
  for (int kt = 0; kt < C_; kt += 64) {
    __syncthreads();
    #pragma unroll
    for (int j = 0; j < 4; j++) {
      const int row = wave * 8 + j * 64 + h3r;   // (row & 7) == h3r
      gload16(&A[(size_t)(m0 + row) * C_ + kt + scg], &As[wave * 8 + j * 64][0]);
    }
    // B staging: raw xT us8 (linear chunk) -> GN affine -> swizzled ds_write
    {
      const int cbase = kt + (lane & 7) * 8;
      float2 sv[8];
      #pragma unroll
      for (int e = 0; e < 8; e++) sv[e] = sb[cbase + e];
      #pragma unroll
      for (int j = 0; j < 2; j++) {
        const int row = wave * 8 + j * 64 + h3r;
        const us8 xr = *(const us8*)&Bb[(size_t)(n0 + row) * C_ + cbase];
        us8 o;
        #pragma unroll
        for (int e = 0; e < 8; e++) o[e] = f2bf(bf2f(xr[e]) * sv[e].x + sv[e].y);
        *(us8*)&Bs[row][((lane & 7) ^ h3r) * 8] = o;
      }
    }
    __syncthreads();
    #pragma unroll
    for (int kk = 0; kk < 2; kk++) {
      bf16x8 af[4], bfr[4];
      #pragma unroll
      for (int mi = 0; mi < 4; mi++)
        af[mi] = *(const bf16x8*)&As[wm + mi * 16 + l16][(((kk << 2) | lq) ^ rdx) * 8];
      #pragma unroll
      for (int ni = 0; ni < 4; ni++)
        bfr[ni] = *(const bf16x8*)&Bs[wn + ni * 16 + l16][(((kk << 2) | lq) ^ rdx) * 8];
      #pragma unroll
      for (int mi = 0; mi < 4; mi++)
        #pragma unroll
        for (int ni = 0; ni < 4; ni++)
          acc[mi][ni] = __builtin_amdgcn_mfma_f32_16x16x32_bf16(af[mi], bfr[ni], acc[mi][ni], 0, 0, 0);
    }
  }
  #pragma unroll
  for (int mi = 0; mi < 4; mi++) {
    const int row0 = m0 + wm + mi * 16 + lq * 4;
    #pragma unroll
    for (int ni = 0; ni < 4; ni++) {
      const int col = n0 + wn + ni * 16 + l16;
      const int which = row0 >> 9;           // 0=q, 1=k, 2=v
      if (which < 2) {
        const int h = (row0 >> 6) & 7, d0 = row0 & 63;
        u16* dst = which ? kT : qT;
        us4 o;
        #pragma unroll
        for (int j = 0; j < 4; j++) o[j] = f2bf(acc[mi][ni][j]);
        *(us4*)&dst[((size_t)((bz * H_ + h) * N_) + col) * D_ + d0] = o;
      } else {
        // n-permute within 64-group: n = g32 + hi*16 + lq2*4 + j -> g32 + lq2*8 + hi*4 + j
        const int cp = (col & ~63) | (col & 32) | (((col >> 2) & 3) << 3) |
                       (((col >> 4) & 1) << 2) | (col & 3);
        #pragma unroll
        for (int j = 0; j < 4; j++)
          vout[((size_t)(bz * 512) + (row0 & 511) + j) * N_ + cp] = f2bf(acc[mi][ni][j]);
      }
    }
  }
}

// ---------------- out-proj GEMM with fused combine: B = (po0+po1)*rl staged in-kernel ----------------
__global__ __launch_bounds__(256) void gemm_out_fused(
    const u16* __restrict__ A, const u16* __restrict__ po0, const u16* __restrict__ po1,
    const float* __restrict__ pl, float* __restrict__ C, const float* __restrict__ bias) {
  __shared__ u16 As[128][64];
  __shared__ u16 Bs[128][64];
  const int tid = threadIdx.x;
  const int wave = tid >> 6, lane = tid & 63;
  const int l16 = lane & 15, lq = lane >> 4;

  // XCD-chunked bijective swizzle over grid (4,18,4) = 288 (288%8==0).
  const int lin = blockIdx.x + 4 * (blockIdx.y + 18 * blockIdx.z);
  const int per = 288 >> 3;
  const int eff = (lin & 7) * per + (lin >> 3);
  const int m0 = (eff % 4) * 128;
  const int n0 = ((eff / 4) % 18) * 128;
  const int bz = eff / 72;

  const int wm = (wave >> 1) * 64, wn = (wave & 1) * 64;

  f32x4 acc[4][4];
  #pragma unroll
  for (int mi = 0; mi < 4; mi++)
    #pragma unroll
    for (int ni = 0; ni < 4; ni++) {
      acc[mi][ni][0] = 0.f; acc[mi][ni][1] = 0.f; acc[mi][ni][2] = 0.f; acc[mi][ni][3] = 0.f;
    }

  const int h3r = lane >> 3;
  const int scg = ((lane & 7) ^ h3r) * 8;
  const int rdx = l16 & 7;
  const size_t lstr = (size_t)B_ * H_ * N_;
  for (int kt = 0; kt < C_; kt += 64) {
    __syncthreads();
    #pragma unroll
    for (int j = 0; j < 4; j++) {
      const int row = wave * 8 + j * 32 + h3r;
      gload16(&A[(size_t)(m0 + row) * C_ + kt + scg], &As[wave * 8 + j * 32][0]);
    }
    #pragma unroll
    for (int j = 0; j < 4; j++) {
      const int row = wave * 8 + j * 32 + h3r;
      const size_t pbase = ((size_t)(bz * N_) + n0 + row) * 512 + kt + (lane & 7) * 8;
      const us8 a = *(const us8*)&po0[pbase];
      const us8 c2 = *(const us8*)&po1[pbase];
      const size_t lidx = ((size_t)(bz * H_) + (kt >> 6)) * N_ + n0 + row;
      const float rl = 1.0f / (pl[lidx] + pl[lidx + lstr]);
      us8 o;
      #pragma unroll
      for (int e = 0; e < 8; e++) o[e] = f2bf((bf2f(a[e]) + bf2f(c2[e])) * rl);
      *(us8*)&Bs[row][((lane & 7) ^ h3r) * 8] = o;
    }
    __syncthreads();
    #pragma unroll
    for (int kk = 0; kk < 2; kk++) {
      bf16x8 af[4], bfr[4];
      #pragma unroll
      for (int mi = 0; mi < 4; mi++)
        af[mi] = *(const bf16x8*)&As[wm + mi * 16 + l16][(((kk << 2) | lq) ^ rdx) * 8];
      #pragma unroll
      for (int ni = 0; ni < 4; ni++)
        bfr[ni] = *(const bf16x8*)&Bs[wn + ni * 16 + l16][(((kk << 2) | lq) ^ rdx) * 8];
      #pragma unroll
      for (int mi = 0; mi < 4; mi++)
        #pragma unroll
        for (int ni = 0; ni < 4; ni++)
          acc[mi][ni] = __builtin_amdgcn_mfma_f32_16x16x32_bf16(af[mi], bfr[ni], acc[mi][ni], 0, 0, 0);
    }
  }
  #pragma unroll
  for (int mi = 0; mi < 4; mi++) {
    const int row0 = m0 + wm + mi * 16 + lq * 4;
    #pragma unroll
    for (int ni = 0; ni < 4; ni++) {
      const int col = n0 + wn + ni * 16 + l16;
      #pragma unroll
      for (int j = 0; j < 4; j++) {
        const size_t idx = ((size_t)bz * C_ + row0 + j) * N_ + col;
        C[idx] = acc[mi][ni][j] + bias[row0 + j];
      }
    }
  }
}

// ---------------- flash attention (r14, unchanged): global_load_lds, swizzled source ----------------
__global__ __launch_bounds__(512) void attn_kernel14(
    const u16* __restrict__ qT, const u16* __restrict__ kT,
    const u16* __restrict__ vp, u16* __restrict__ po0,
    float* __restrict__ pl) {
  __shared__ u16 Ks[2][64][64];
  __shared__ u16 Vs[2][64][64];

  const int h = blockIdx.x;
  const int b = blockIdx.z >> 1, sp = blockIdx.z & 1;
  const int q0 = blockIdx.y * 128;
  const int tid = threadIdx.x;
  const int wave = tid >> 6, lane = tid & 63;
  const int l16 = lane & 15, lq = lane >> 4;
  const int h3 = l16 & 7;                  // read-side XOR key
  const int kt0 = sp * NT;

  bf16x8 qf[2];
  {
    const u16* qb = qT + ((size_t)((b * H_ + h) * N_ + q0 + wave * 16 + l16)) * D_;
    qf[0] = *(const bf16x8*)(qb + lq * 8);
    qf[1] = *(const bf16x8*)(qb + 32 + lq * 8);
  }

  float l = 0.f;
  f32x4 acc[4];
  #pragma unroll
  for (int di = 0; di < 4; di++) {
    acc[di][0] = 0.f; acc[di][1] = 0.f; acc[di][2] = 0.f; acc[di][3] = 0.f;
  }
  const f32x4 z4 = {0.f, 0.f, 0.f, 0.f};

  const u16* kbase = kT + (size_t)(b * H_ + h) * N_ * D_;
  const u16* vbase = vp + ((size_t)(b * 512) + h * D_) * N_;
  const int srow = wave * 8 + (lane >> 3);
  const int scg  = (((lane & 7) ^ (srow & 7))) * 8;

  gload16(&kbase[(size_t)(kt0 * 64 + srow) * D_ + scg], &Ks[0][wave * 8][0]);
  gload16(&vbase[(size_t)srow * N_ + kt0 * 64 + scg],   &Vs[0][wave * 8][0]);

  int cur = 0;
  for (int t = 0; t < NT; t++) {
    const int kt = kt0 + t;
    __syncthreads();

    if (t + 1 < NT) {
      gload16(&kbase[(size_t)((kt + 1) * 64 + srow) * D_ + scg], &Ks[cur ^ 1][wave * 8][0]);
      gload16(&vbase[(size_t)srow * N_ + (kt + 1) * 64 + scg],   &Vs[cur ^ 1][wave * 8][0]);
    }

    // ---- S^T = K Q^T ----
    f32x4 s[4];
    __builtin_amdgcn_s_setprio(1);
    #pragma unroll
    for (int ni = 0; ni < 4; ni++) {
      const bf16x8 k0 = *(const bf16x8*)&Ks[cur][ni * 16 + l16][(lq ^ h3) * 8];
      const bf16x8 k1 = *(const bf16x8*)&Ks[cur][ni * 16 + l16][((4 | lq) ^ h3) * 8];
      s[ni] = __builtin_amdgcn_mfma_f32_16x16x32_bf16(k0, qf[0], z4, 0, 0, 0);
      s[ni] = __builtin_amdgcn_mfma_f32_16x16x32_bf16(k1, qf[1], s[ni], 0, 0, 0);
    }
    __builtin_amdgcn_s_setprio(0);

    // ---- p = exp2(s); l in-lane; pack directly into PV a-frag words ----
    union { u32 w[4]; bf16x8 v; } af[2];
    float rs = 0.f;
    #pragma unroll
    for (int ni = 0; ni < 4; ni++) {
      const float p0 = __builtin_amdgcn_exp2f(s[ni][0]);
      const float p1 = __builtin_amdgcn_exp2f(s[ni][1]);
      const float p2 = __builtin_amdgcn_exp2f(s[ni][2]);
      const float p3 = __builtin_amdgcn_exp2f(s[ni][3]);
      rs += (p0 + p1) + (p2 + p3);
      af[ni >> 1].w[(ni & 1) * 2]     = pack2bf(p0, p1);
      af[ni >> 1].w[(ni & 1) * 2 + 1] = pack2bf(p2, p3);
    }
    l += rs;

    // ---- PV ----
    __builtin_amdgcn_s_setprio(1);
    #pragma unroll
    for (int kh = 0; kh < 2; kh++)
      #pragma unroll
      for (int di = 0; di < 4; di++) {
        const bf16x8 vf = *(const bf16x8*)&Vs[cur][di * 16 + l16][(((kh << 2) | lq) ^ h3) * 8];
        acc[di] = __builtin_amdgcn_mfma_f32_16x16x32_bf16(af[kh].v, vf, acc[di], 0, 0, 0);
      }
    __builtin_amdgcn_s_setprio(0);

    cur ^= 1;
  }

  // ---- epilogue: write unnormalized partial O (bf16) + partial l ----
  u16* po = po0 + (size_t)sp * ((size_t)B_ * N_ * 512);
  l += __shfl_xor(l, 16);
  l += __shfl_xor(l, 32);
  if (lq == 0) {
    const int n = q0 + wave * 16 + l16;
    pl[((size_t)((sp * B_ + b) * H_) + h) * N_ + n] = l;
  }
  #pragma unroll
  for (int di = 0; di < 4; di++)
    #pragma unroll
    for (int j = 0; j < 4; j++) {
      const int n = q0 + wave * 16 + lq * 4 + j;
      po[((size_t)(b * N_) + n) * 512 + h * D_ + di * 16 + l16] = f2bf(acc[di][j]);
    }
}

extern "C" void kernel_launch(void* const* d_in, const int* in_sizes, int n_in,
                              void* d_out, int out_size, void* d_ws, size_t ws_size,
                              hipStream_t stream) {
  const float* x     = (const float*)d_in[0];
  const float* gamma = (const float*)d_in[1];
  const float* beta  = (const float*)d_in[2];
  const float* w_qkv = (const float*)d_in[3];
  const float* w_out = (const float*)d_in[4];
  const float* b_out = (const float*)d_in[5];
  float* out = (float*)d_out;

  char* ws = (char*)d_ws;
  u16*    xT     = (u16*)(ws + 0);          // dead after gemm_qkv
  u16*    wq_bf  = (u16*)(ws + 9437184);
  u16*    po0    = (u16*)(ws + 11010048);
  u16*    po1    = (u16*)(ws + 20447232);
  u16*    vsec   = (u16*)(ws + 37748736);
  u16*    qT     = (u16*)(ws + 47185920);
  u16*    kT     = (u16*)(ws + 56623104);
  float*  pl     = (float*)(ws + 66060288);
  float2* part   = (float2*)(ws + 66650112);
  u16*    wo_bf  = (u16*)(ws + 66686976);
  float2* scsh   = (float2*)(ws + 67211264);

  prep_all<<<dim3(1408), dim3(256), 0, stream>>>(w_qkv, w_out, wq_bf, wo_bf, x, xT, part);
  make_scsh<<<dim3(B_), dim3(512), 0, stream>>>(part, gamma, beta, scsh);
  gemm_qkv<<<dim3(6, 18, B_), dim3(512), 0, stream>>>(wq_bf, xT, scsh, qT, kT, vsec);
  attn_kernel14<<<dim3(H_, N_ / 128, B_ * SPLIT), dim3(512), 0, stream>>>(qT, kT, vsec, po0, pl);
  gemm_out_fused<<<dim3(4, 18, B_), dim3(256), 0, stream>>>(wo_bf, po0, po1, pl, out, b_out);
}